// Round 12
// baseline (1050.725 us; speedup 1.0000x reference)
//
#include <hip/hip_runtime.h>

using u16 = unsigned short;
typedef __bf16 bf16x8 __attribute__((ext_vector_type(8)));
typedef float f32x4 __attribute__((ext_vector_type(4)));

__device__ inline u16 f2bf(float f){
  unsigned u = __float_as_uint(f);
  u += 0x7fff + ((u >> 16) & 1);   // RNE
  return (u16)(u >> 16);
}
__device__ inline float bf2f(u16 u){ return __uint_as_float((unsigned)u << 16); }

__device__ inline float wredsum(float v){
  #pragma unroll
  for (int o = 32; o; o >>= 1) v += __shfl_xor(v, o, 64);
  return v;
}
__device__ inline float wredmax(float v){
  #pragma unroll
  for (int o = 32; o; o >>= 1) v = fmaxf(v, __shfl_xor(v, o, 64));
  return v;
}

// direct global -> LDS DMA, 16B per lane; lds base must be wave-uniform
__device__ inline void gld16(const u16* g, u16* lds){
  __builtin_amdgcn_global_load_lds(
      (const __attribute__((address_space(1))) unsigned int*)g,
      (__attribute__((address_space(3))) unsigned int*)lds, 16, 0, 0);
}

// ---------------- mod matvec: out = silu(vec) @ W + b, W is 2048x12288 ----------------
__global__ void mod_matvec_k(const float* __restrict__ vec,
    const float* __restrict__ wi, const float* __restrict__ bi,
    const float* __restrict__ wt, const float* __restrict__ bt,
    float* __restrict__ oi, float* __restrict__ ot)
{
  __shared__ float sv[2048];
  __shared__ float red[4][64];
  int tid = threadIdx.x;
  for (int i = tid; i < 2048; i += 256){ float v = vec[i]; sv[i] = v / (1.0f + __expf(-v)); }
  __syncthreads();
  int j0 = blockIdx.x * 64;
  bool ist = j0 >= 12288;
  const float* w = ist ? wt : wi;
  const float* b = ist ? bt : bi;
  float* o = ist ? ot : oi;
  int col = (ist ? j0 - 12288 : j0) + (tid & 63);
  int kq = tid >> 6;
  float acc = 0.f;
  const float* wp = w + col;
  for (int k = kq * 512; k < kq * 512 + 512; ++k) acc += sv[k] * wp[(long long)k * 12288];
  red[kq][tid & 63] = acc;
  __syncthreads();
  if (kq == 0){
    o[col] = red[0][tid] + red[1][tid] + red[2][tid] + red[3][tid] + b[col];
  }
}

// ---------------- merged transpose + cast: 8 weights, (K x N) f32 -> (N x K) bf16 ----------------
struct TcArgs {
  const float* in[8];
  u16* out[8];
  int K[8];
  int N[8];
  int base[9];   // prefix of 32x32-tile counts
};

__global__ void tcast8_k(TcArgs a)
{
  __shared__ float tile[32][33];
  int bid = blockIdx.x;
  int w = 0;
  #pragma unroll
  for (int i = 0; i < 8; ++i) if (bid >= a.base[i + 1]) w = i + 1;
  const float* in = a.in[w];
  u16* out = a.out[w];
  int K = a.K[w], N = a.N[w];
  int local = bid - a.base[w];
  int tx = N >> 5;
  int n0 = (local % tx) * 32, k0 = (local / tx) * 32;
  int tid = threadIdx.x;
  int r = tid >> 3, c4 = (tid & 7) * 4;
  float4 v = *(const float4*)&in[(long long)(k0 + r) * N + n0 + c4];
  tile[r][c4 + 0] = v.x; tile[r][c4 + 1] = v.y; tile[r][c4 + 2] = v.z; tile[r][c4 + 3] = v.w;
  __syncthreads();
  int n = tid >> 3, kq = (tid & 7) * 4;
  ushort4 o;
  o.x = f2bf(tile[kq + 0][n]);
  o.y = f2bf(tile[kq + 1][n]);
  o.z = f2bf(tile[kq + 2][n]);
  o.w = f2bf(tile[kq + 3][n]);
  *(ushort4*)&out[(long long)(n0 + n) * K + k0 + kq] = o;
}

// ---------------- LayerNorm + modulate: out = (1+sc)*LN(x) + sh  (2048 cols) ----------------
__global__ void ln_mod_k(const float* __restrict__ x,
    const float* __restrict__ sh, const float* __restrict__ sc,
    u16* __restrict__ out)
{
  int row = blockIdx.x, tid = threadIdx.x;
  const float* xr = x + (long long)row * 2048;
  float v[8]; float s = 0.f, s2 = 0.f;
  #pragma unroll
  for (int j = 0; j < 8; ++j){ v[j] = xr[tid + j * 256]; s += v[j]; s2 += v[j] * v[j]; }
  s = wredsum(s); s2 = wredsum(s2);
  __shared__ float red[4][2];
  int wave = tid >> 6, lane = tid & 63;
  if (lane == 0){ red[wave][0] = s; red[wave][1] = s2; }
  __syncthreads();
  float S1 = red[0][0] + red[1][0] + red[2][0] + red[3][0];
  float S2 = red[0][1] + red[1][1] + red[2][1] + red[3][1];
  float mu = S1 * (1.0f / 2048.0f);
  float var = S2 * (1.0f / 2048.0f) - mu * mu;
  float rs = rsqrtf(var + 1e-6f);
  u16* orow = out + (long long)row * 2048;
  #pragma unroll
  for (int j = 0; j < 8; ++j){
    int c = tid + j * 256;
    orow[c] = f2bf((1.0f + sc[c]) * (v[j] - mu) * rs + sh[c]);
  }
}

// ---------------- QKV post: RMSNorm(q,k) + RoPE + scatter to Q/K [h][pos][d], Vt [h][d][pos] ----------------
__global__ void qkv_post_k(const float* __restrict__ qkv, int pos0,
    const float* __restrict__ qs, const float* __restrict__ ks,
    const float* __restrict__ pe,
    u16* __restrict__ Q, u16* __restrict__ Ko, u16* __restrict__ Vt)
{
  __shared__ u16 vs[128][72];
  int h = blockIdx.y;
  int t0 = blockIdx.x * 64;
  int tid = threadIdx.x, wave = tid >> 6, lane = tid & 63;
  for (int it = 0; it < 16; ++it){
    int tl = it * 4 + wave;
    int t = t0 + tl;
    const float* rp = qkv + (long long)t * 6144 + h * 128;
    float q0 = rp[lane],        q1 = rp[lane + 64];
    float k0 = rp[2048 + lane], k1 = rp[2048 + lane + 64];
    float v0 = rp[4096 + lane], v1 = rp[4096 + lane + 64];
    float qss = wredsum(q0 * q0 + q1 * q1);
    float kss = wredsum(k0 * k0 + k1 * k1);
    float rq = rsqrtf(qss * (1.0f / 128.0f) + 1e-6f) * 0.08838834764831845f; // incl 1/sqrt(DH)
    float rk = rsqrtf(kss * (1.0f / 128.0f) + 1e-6f);
    float qn0 = q0 * rq * qs[lane], qn1 = q1 * rq * qs[lane + 64];
    float kn0 = k0 * rk * ks[lane], kn1 = k1 * rk * ks[lane + 64];
    int pos = pos0 + t;
    const float* peb = pe + (long long)pos * 256;
    bool odd = lane & 1;
    float4 p0 = *(const float4*)&peb[(lane >> 1) * 4];
    float4 p1 = *(const float4*)&peb[128 + (lane >> 1) * 4];
    float c00 = odd ? p0.z : p0.x, c01 = odd ? p0.w : p0.y;
    float c10 = odd ? p1.z : p1.x, c11 = odd ? p1.w : p1.y;
    float qp0 = __shfl_xor(qn0, 1, 64), qp1 = __shfl_xor(qn1, 1, 64);
    float kp0 = __shfl_xor(kn0, 1, 64), kp1 = __shfl_xor(kn1, 1, 64);
    float qe0 = odd ? qp0 : qn0, qo0 = odd ? qn0 : qp0;
    float qe1 = odd ? qp1 : qn1, qo1 = odd ? qn1 : qp1;
    float ke0 = odd ? kp0 : kn0, ko0 = odd ? kn0 : kp0;
    float ke1 = odd ? kp1 : kn1, ko1 = odd ? kn1 : kp1;
    u16* Qr = Q  + ((long long)h * 2304 + pos) * 128;
    u16* Kr = Ko + ((long long)h * 2304 + pos) * 128;
    Qr[lane]      = f2bf(c00 * qe0 + c01 * qo0);
    Qr[lane + 64] = f2bf(c10 * qe1 + c11 * qo1);
    Kr[lane]      = f2bf(c00 * ke0 + c01 * ko0);
    Kr[lane + 64] = f2bf(c10 * ke1 + c11 * ko1);
    vs[lane][tl]      = f2bf(v0);
    vs[lane + 64][tl] = f2bf(v1);
  }
  __syncthreads();
  int dd = tid >> 1, co = (tid & 1) * 32;
  u16* vr = Vt + ((long long)h * 128 + dd) * 2304 + pos0 + t0 + co;
  #pragma unroll
  for (int u = 0; u < 8; ++u)
    *(ushort4*)(vr + u * 4) = *(const ushort4*)&vs[dd][co + u * 4];
}

// ---------------- softmax per bf16 row (2304), in-place ----------------
__global__ void softmax16_k(u16* __restrict__ S)
{
  long long base = (long long)blockIdx.y * 2304 * 2304 + (long long)blockIdx.x * 2304;
  u16* row = S + base;
  int tid = threadIdx.x;
  float v[9]; float m = -3.0e38f;
  #pragma unroll
  for (int j = 0; j < 9; ++j){ v[j] = bf2f(row[tid + j * 256]); m = fmaxf(m, v[j]); }
  m = wredmax(m);
  __shared__ float red[4];
  int wave = tid >> 6, lane = tid & 63;
  if (lane == 0) red[wave] = m;
  __syncthreads();
  m = fmaxf(fmaxf(red[0], red[1]), fmaxf(red[2], red[3]));
  float s = 0.f;
  #pragma unroll
  for (int j = 0; j < 9; ++j){ v[j] = __expf(v[j] - m); s += v[j]; }
  s = wredsum(s);
  __syncthreads();
  if (lane == 0) red[wave] = s;
  __syncthreads();
  s = red[0] + red[1] + red[2] + red[3];
  float r = 1.0f / s;
  #pragma unroll
  for (int j = 0; j < 9; ++j) row[tid + j * 256] = f2bf(v[j] * r);
}

// ======== 8-phase pipelined GEMM (m201 template), BM=256, BK=64, 8 waves, img+txt merged ========
// Grid x: 0..7 = img row-blocks (M=2048), 8 = txt (M=256, exactly one 256-row block).
// Half-tile stream H[4t+{0,1,2,3}] = {A-half0,B-half0,A-half1,B-half1} of K-tile t.
// Phase (t,q) computes quadrant (mh=q>>1, nh=q&1) of tile t from buf[t&1] AND issues
// stage H[4t+q+6] (q0:A1(t+1) q1:B1(t+1) q2:A0(t+2) q3:B0(t+2)) -- slot-freeing verified:
// each slot's re-write is issued exactly one closing-barrier after its last read.
// ONE counted vmcnt per tile at q0: allows newest 3 half-tiles in flight =
// vmcnt(6) for BN=256 (2+2+2 loads) / vmcnt(5) for BN=128 (2+1+2); vmcnt(0) last tile only.
// Per phase: stage -> [vmcnt] -> barrier -> ds_read quadrant (XOR-swizzled) ->
// lgkmcnt(0)+sched_barrier -> setprio(1) MFMA setprio(0) -> barrier.
// MODE 0: f32 = acc+bias ; 2: f32 = res + gate[col]*(acc+bias) ; 3: bf16 = gelu(acc+bias)
template<int BN, int MODE>
__global__ __launch_bounds__(512)
void gemm9_k(const u16* __restrict__ Ai, const u16* __restrict__ At, int lda,
             const u16* __restrict__ Bi, const u16* __restrict__ Bt, int ldb,
             const float* __restrict__ bias_i, const float* __restrict__ bias_t,
             const float* __restrict__ res_i,  const float* __restrict__ res_t,
             const float* __restrict__ gate_i, const float* __restrict__ gate_t,
             void* __restrict__ Ci, void* __restrict__ Ct, int ldc, int K)
{
  constexpr int BK  = 64;
  constexpr int BNH = BN / 2;                 // B half rows
  constexpr int WM  = (BN == 256) ? 2 : 4;    // wave grid
  constexpr int WN  = 8 / WM;
  constexpr int MRH = 128 / (WM * 16);        // A frags per half per wave (4 / 2)
  constexpr int NRH = BNH / (WN * 16);        // B frags per half per wave (2 / 2)
  constexpr int BL  = (BNH == 128) ? 2 : 1;   // loads per B-half per thread

  __shared__ u16 Ah[2][2][128 * BK];          // [buf][half]
  __shared__ u16 Bh[2][2][BNH * BK];

  const int tid  = threadIdx.x;
  const int lane = tid & 63;
  const int wave = tid >> 6;
  const int wm   = wave % WM;
  const int wn   = wave / WM;

  const int bx = blockIdx.x;                  // 0..8 ; 8 = txt
  const int by = blockIdx.y;
  const bool ist = (bx == 8);
  const u16* Ab = ist ? At : (Ai + (long long)bx * 256 * lda);
  const u16* Bb = (ist ? Bt : Bi) + (long long)by * BN * ldb;
  const float* bias = ist ? bias_t : bias_i;
  const float* res  = ist ? res_t  : res_i;
  const float* gate = ist ? gate_t : gate_i;
  void* C = ist ? Ct : Ci;

  // staging geometry: each 64-row unit staged by 512 threads (wave w rows [w*8,w*8+8),
  // lane l -> row +(l>>3), dest octet l&7). Global octet pre-swizzled by (l&7)^((l>>3)&7)
  // so LDS holds lds[r][g] = glob[r][g ^ (r&7)] (involution; 0 bank conflicts, R9).
  const int srow = wave * 8 + (lane >> 3);
  const int sgo  = ((lane & 7) ^ ((lane >> 3) & 7)) * 8;   // u16 units

  auto stageA = [&](int h, int b, int kk){
    #pragma unroll
    for (int j = 0; j < 2; ++j)
      gld16(Ab + (long long)(h * 128 + j * 64 + srow) * lda + kk + sgo,
            &Ah[b][h][(j * 64 + wave * 8) * BK]);
  };
  auto stageB = [&](int h, int b, int kk){
    #pragma unroll
    for (int j = 0; j < BL; ++j)
      gld16(Bb + (long long)(h * BNH + j * 64 + srow) * ldb + kk + sgo,
            &Bh[b][h][(j * 64 + wave * 8) * BK]);
  };

  const int frow = lane & 15;
  const int fx   = lane & 7;
  const int j0   = lane >> 4;

  f32x4 acc[2 * MRH][2 * NRH] = {};

  const int nt = K / BK;                      // >= 32 for all launches here
  // prologue: H0..H5 = A0,B0,A1,B1 of tile0 + A0,B0 of tile1
  stageA(0, 0, 0); stageB(0, 0, 0); stageA(1, 0, 0); stageB(1, 0, 0);
  stageA(0, 1, BK); stageB(0, 1, BK);
  __builtin_amdgcn_sched_barrier(0);

  for (int t = 0; t < nt; ++t){
    const int b = t & 1;
    #pragma unroll
    for (int q = 0; q < 4; ++q){
      if      (q == 0){ if (t + 1 < nt) stageA(1, (t + 1) & 1, (t + 1) * BK); }
      else if (q == 1){ if (t + 1 < nt) stageB(1, (t + 1) & 1, (t + 1) * BK); }
      else if (q == 2){ if (t + 2 < nt) stageA(0, b, (t + 2) * BK); }
      else            { if (t + 2 < nt) stageB(0, b, (t + 2) * BK); }
      __builtin_amdgcn_sched_barrier(0);
      if (q == 0){
        if (t == nt - 1)              asm volatile("s_waitcnt vmcnt(0)" ::: "memory");
        else if constexpr (BN == 256) asm volatile("s_waitcnt vmcnt(6)" ::: "memory");
        else                          asm volatile("s_waitcnt vmcnt(5)" ::: "memory");
        __builtin_amdgcn_sched_barrier(0);
      }
      __builtin_amdgcn_s_barrier();           // tile t resident (q0) / prev reads done
      __builtin_amdgcn_sched_barrier(0);

      const int mh = q >> 1, nh = q & 1;
      const u16* as = Ah[b][mh];
      const u16* bs = Bh[b][nh];
      bf16x8 af[2][MRH], bfr[2][NRH];
      #pragma unroll
      for (int s = 0; s < 2; ++s){
        const int oct = ((s * 4 + j0) ^ fx) * 8;
        #pragma unroll
        for (int i = 0; i < MRH; ++i)
          af[s][i] = *(const bf16x8*)&as[(wm * (128 / WM) + i * 16 + frow) * BK + oct];
        #pragma unroll
        for (int i = 0; i < NRH; ++i)
          bfr[s][i] = *(const bf16x8*)&bs[(wn * 32 + i * 16 + frow) * BK + oct];
      }
      asm volatile("s_waitcnt lgkmcnt(0)" ::: "memory");
      __builtin_amdgcn_sched_barrier(0);
      __builtin_amdgcn_s_setprio(1);
      #pragma unroll
      for (int s = 0; s < 2; ++s)
        #pragma unroll
        for (int i = 0; i < MRH; ++i)
          #pragma unroll
          for (int k2 = 0; k2 < NRH; ++k2)
            acc[mh * MRH + i][nh * NRH + k2] = __builtin_amdgcn_mfma_f32_16x16x32_bf16(
                af[s][i], bfr[s][k2], acc[mh * MRH + i][nh * NRH + k2], 0, 0, 0);
      __builtin_amdgcn_s_setprio(0);
      __builtin_amdgcn_sched_barrier(0);
      __builtin_amdgcn_s_barrier();           // phase reads done -> slots freed
      __builtin_amdgcn_sched_barrier(0);
    }
  }

  const int lr = (lane >> 4) * 4;
  const int lc = lane & 15;
  const long long rowbase = ist ? 0 : (long long)bx * 256;
  #pragma unroll
  for (int m = 0; m < 2 * MRH; ++m){
    const int mh = m / MRH, im = m % MRH;
    #pragma unroll
    for (int n = 0; n < 2 * NRH; ++n){
      const int nh = n / NRH, in_ = n % NRH;
      long long col = (long long)by * BN + nh * BNH + wn * 32 + in_ * 16 + lc;
      float bv = bias ? bias[col] : 0.0f;
      #pragma unroll
      for (int jj = 0; jj < 4; ++jj){
        long long row = rowbase + mh * 128 + wm * (128 / WM) + im * 16 + lr + jj;
        float v = acc[m][n][jj] + bv;
        long long ci = row * (long long)ldc + col;
        if constexpr (MODE == 0) ((float*)C)[ci] = v;
        else if constexpr (MODE == 2) ((float*)C)[ci] = res[ci] + gate[col] * v;
        else {
          float z2 = 1.5957691216057308f * (v + 0.044715f * v * v * v);
          ((u16*)C)[ci] = f2bf(v / (1.0f + __expf(-z2)));
        }
      }
    }
  }
}

// ---------------- generic bf16 MFMA GEMM, 2-phase double-buffered (attention) ----------------
// MODE 0: f32 out ; 1: bf16 out
template<int BM, int BN, int MODE>
__global__ __launch_bounds__(256)
void gemm_k(const u16* __restrict__ A, int lda, long long abstr,
            const u16* __restrict__ B, int ldb, long long bbstr,
            void* __restrict__ C, int ldc, long long cbstr,
            int K)
{
  constexpr int BK  = 32;
  constexpr int WGM = BM / 64;       // waves along M (1 or 2)
  constexpr int WGN = 4 / WGM;       // waves along N
  constexpr int WTN = BN / WGN;      // wave tile N
  constexpr int NFR = WTN / 16;      // n-frags per wave
  constexpr int CA  = BM / 64;       // A staging chunks per wave (16 rows each)
  constexpr int CB  = BN / 64;       // B staging chunks per wave

  __shared__ u16 As[2][BM * BK];
  __shared__ u16 Bs[2][BN * BK];
  const int tid  = threadIdx.x;
  const int lane = tid & 63;
  const int wave = tid >> 6;
  const int wr = (wave / WGN) * 64;
  const int wc = (wave % WGN) * WTN;

  const u16* Ab = A + (long long)blockIdx.z * abstr + (long long)blockIdx.x * BM * lda;
  const u16* Bb = B + (long long)blockIdx.z * bbstr + (long long)blockIdx.y * BN * ldb;

  const int srow = lane >> 2;
  const int scol = (lane & 3) * 8;
  const u16* agp[CA]; int aro[CA];
  const u16* bgp[CB]; int bro[CB];
  #pragma unroll
  for (int c = 0; c < CA; ++c){
    int r0 = (c * 4 + wave) * 16;
    agp[c] = Ab + (long long)(r0 + srow) * lda + scol;
    aro[c] = r0 * BK;
  }
  #pragma unroll
  for (int c = 0; c < CB; ++c){
    int r0 = (c * 4 + wave) * 16;
    bgp[c] = Bb + (long long)(r0 + srow) * ldb + scol;
    bro[c] = r0 * BK;
  }

  #pragma unroll
  for (int c = 0; c < CA; ++c) gld16(agp[c], &As[0][aro[c]]);
  #pragma unroll
  for (int c = 0; c < CB; ++c) gld16(bgp[c], &Bs[0][bro[c]]);
  __syncthreads();

  f32x4 acc[4][NFR] = {};
  const int nt = K / BK;
  int cur = 0;
  for (int t = 0; t < nt; ++t){
    int nxt = cur ^ 1;
    if (t + 1 < nt){
      int ko = (t + 1) * BK;
      #pragma unroll
      for (int c = 0; c < CA; ++c) gld16(agp[c] + ko, &As[nxt][aro[c]]);
      #pragma unroll
      for (int c = 0; c < CB; ++c) gld16(bgp[c] + ko, &Bs[nxt][bro[c]]);
    }
    bf16x8 af[4], bfr[NFR];
    #pragma unroll
    for (int i = 0; i < 4; ++i)
      af[i] = *(const bf16x8*)&As[cur][(wr + i * 16 + (lane & 15)) * BK + (lane >> 4) * 8];
    #pragma unroll
    for (int i = 0; i < NFR; ++i)
      bfr[i] = *(const bf16x8*)&Bs[cur][(wc + i * 16 + (lane & 15)) * BK + (lane >> 4) * 8];
    #pragma unroll
    for (int mi = 0; mi < 4; ++mi)
      #pragma unroll
      for (int ni = 0; ni < NFR; ++ni)
        acc[mi][ni] = __builtin_amdgcn_mfma_f32_16x16x32_bf16(af[mi], bfr[ni], acc[mi][ni], 0, 0, 0);
    __syncthreads();
    cur = nxt;
  }

  const int lr = (lane >> 4) * 4;
  const int lc = lane & 15;
  const long long rowb = (long long)blockIdx.x * BM + wr;
  const long long colb = (long long)blockIdx.y * BN + wc;
  const long long cb = (long long)blockIdx.z * cbstr;
  #pragma unroll
  for (int mi = 0; mi < 4; ++mi){
    #pragma unroll
    for (int ni = 0; ni < NFR; ++ni){
      long long col = colb + ni * 16 + lc;
      #pragma unroll
      for (int j = 0; j < 4; ++j){
        long long row = rowb + mi * 16 + lr + j;
        float v = acc[mi][ni][j];
        long long ci = cb + row * ldc + col;
        if constexpr (MODE == 0) ((float*)C)[ci] = v;
        else ((u16*)C)[ci] = f2bf(v);
      }
    }
  }
}

extern "C" void kernel_launch(void* const* d_in, const int* in_sizes, int n_in,
                              void* d_out, int out_size, void* d_ws, size_t ws_size,
                              hipStream_t stream)
{
  const float* img        = (const float*)d_in[0];
  const float* txt        = (const float*)d_in[1];
  const float* vec        = (const float*)d_in[2];
  const float* img_mod_w  = (const float*)d_in[3];
  const float* img_mod_b  = (const float*)d_in[4];
  const float* txt_mod_w  = (const float*)d_in[5];
  const float* txt_mod_b  = (const float*)d_in[6];
  const float* img_qkv_w  = (const float*)d_in[7];
  const float* img_qkv_b  = (const float*)d_in[8];
  const float* img_q_s    = (const float*)d_in[9];
  const float* img_k_s    = (const float*)d_in[10];
  const float* txt_qkv_w  = (const float*)d_in[11];
  const float* txt_qkv_b  = (const float*)d_in[12];
  const float* txt_q_s    = (const float*)d_in[13];
  const float* txt_k_s    = (const float*)d_in[14];
  const float* img_proj_w = (const float*)d_in[15];
  const float* img_proj_b = (const float*)d_in[16];
  const float* txt_proj_w = (const float*)d_in[17];
  const float* txt_proj_b = (const float*)d_in[18];
  const float* img_mlp_w1 = (const float*)d_in[19];
  const float* img_mlp_b1 = (const float*)d_in[20];
  const float* img_mlp_w2 = (const float*)d_in[21];
  const float* img_mlp_b2 = (const float*)d_in[22];
  const float* txt_mlp_w1 = (const float*)d_in[23];
  const float* txt_mlp_b1 = (const float*)d_in[24];
  const float* txt_mlp_w2 = (const float*)d_in[25];
  const float* txt_mlp_b2 = (const float*)d_in[26];
  const float* pe         = (const float*)d_in[27];

  char* ws = (char*)d_ws;
  size_t off = 0;
  auto alloc = [&](size_t b){ void* p = ws + off; off = (off + b + 255) & ~(size_t)255; return p; };

  u16* wq_i = (u16*)alloc(6144ll * 2048 * 2);
  u16* wq_t = (u16*)alloc(6144ll * 2048 * 2);
  u16* wp_i = (u16*)alloc(2048ll * 2048 * 2);
  u16* wp_t = (u16*)alloc(2048ll * 2048 * 2);
  u16* w1_i = (u16*)alloc(8192ll * 2048 * 2);
  u16* w1_t = (u16*)alloc(8192ll * 2048 * 2);
  u16* w2_i = (u16*)alloc(2048ll * 8192 * 2);
  u16* w2_t = (u16*)alloc(2048ll * 8192 * 2);
  float* mod_i = (float*)alloc(12288 * 4);
  float* mod_t = (float*)alloc(12288 * 4);
  u16* Qb   = (u16*)alloc(16ll * 2304 * 128 * 2);
  u16* Kb   = (u16*)alloc(16ll * 2304 * 128 * 2);
  u16* Vt   = (u16*)alloc(16ll * 2304 * 128 * 2);
  u16* attn = (u16*)alloc(2304ll * 2048 * 2);
  char* big = (char*)alloc(4ll * 2304 * 2304 * 4);   // 84.9 MB reused region

  // optional merged-attention S (all 16 heads, bf16): 162 MB extra
  size_t s16_bytes = 16ll * 2304 * 2304 * 2;
  size_t off_before_s16 = off;
  u16* S16 = (u16*)alloc(s16_bytes);
  const bool merged_attn = (off <= ws_size);
  if (!merged_attn) off = off_before_s16;

  // phase 1 views
  u16*   xin_i = (u16*)big;
  u16*   xin_t = (u16*)(big + 8388608);
  float* qkv_i = (float*)(big + 9437184);
  float* qkv_t = (float*)(big + 59768832);
  // phase 2 fallback view (bf16 S for 4 heads = 42.5 MB)
  u16*   S4   = (u16*)big;
  // phase 3 views
  float* y1_i  = (float*)big;
  float* y1_t  = (float*)(big + 16777216);
  u16*   ln2_i = (u16*)(big + 18874368);
  u16*   ln2_t = (u16*)(big + 27262976);
  u16*   h_i   = (u16*)(big + 28311552);
  u16*   h_t   = (u16*)(big + 61865984);

  // modulation vectors
  mod_matvec_k<<<384, 256, 0, stream>>>(vec, img_mod_w, img_mod_b, txt_mod_w, txt_mod_b, mod_i, mod_t);

  // merged weight cast + transpose to (N x K) bf16 (1 launch instead of 8)
  {
    TcArgs a;
    const float* ins[8] = {img_qkv_w, txt_qkv_w, img_proj_w, txt_proj_w,
                           img_mlp_w1, txt_mlp_w1, img_mlp_w2, txt_mlp_w2};
    u16* outs[8] = {wq_i, wq_t, wp_i, wp_t, w1_i, w1_t, w2_i, w2_t};
    int Ks[8] = {2048, 2048, 2048, 2048, 2048, 2048, 8192, 8192};
    int Ns[8] = {6144, 6144, 2048, 2048, 8192, 8192, 2048, 2048};
    int b = 0;
    for (int i = 0; i < 8; ++i){
      a.in[i] = ins[i]; a.out[i] = outs[i]; a.K[i] = Ks[i]; a.N[i] = Ns[i];
      a.base[i] = b;
      b += (Ks[i] >> 5) * (Ns[i] >> 5);
    }
    a.base[8] = b;
    tcast8_k<<<b, 256, 0, stream>>>(a);
  }

  // LN1 + modulate
  ln_mod_k<<<2048, 256, 0, stream>>>(img, mod_i, mod_i + 2048, xin_i);
  ln_mod_k<<<256,  256, 0, stream>>>(txt, mod_t, mod_t + 2048, xin_t);

  // QKV GEMM (8-phase, img+txt merged: 9x24 = 216 blocks of 256x256)
  gemm9_k<256,0><<<dim3(9, 24), 512, 0, stream>>>(xin_i, xin_t, 2048, wq_i, wq_t, 2048,
      img_qkv_b, txt_qkv_b, nullptr, nullptr, nullptr, nullptr, qkv_i, qkv_t, 6144, 2048);

  // RMSNorm + RoPE + scatter (txt occupies positions 0..255, img 256..2303)
  qkv_post_k<<<dim3(32, 16), 256, 0, stream>>>(qkv_i, 256, img_q_s, img_k_s, pe, Qb, Kb, Vt);
  qkv_post_k<<<dim3(4, 16),  256, 0, stream>>>(qkv_t, 0,   txt_q_s, txt_k_s, pe, Qb, Kb, Vt);

  // attention: QK^T (bf16 S) -> softmax -> PV
  if (merged_attn){
    gemm_k<128,128,1><<<dim3(18, 18, 16), 256, 0, stream>>>(Qb, 128, 2304ll * 128, Kb, 128, 2304ll * 128,
        S16, 2304, 2304ll * 2304, 128);
    softmax16_k<<<dim3(2304, 16), 256, 0, stream>>>(S16);
    gemm_k<128,64,1><<<dim3(18, 2, 16), 256, 0, stream>>>(S16, 2304, 2304ll * 2304, Vt, 2304, 128ll * 2304,
        attn, 2048, 128, 2304);
  } else {
    for (int g = 0; g < 4; ++g){
      const u16* Qg = Qb + (long long)g * 4 * 2304 * 128;
      const u16* Kg = Kb + (long long)g * 4 * 2304 * 128;
      const u16* Vg = Vt + (long long)g * 4 * 128 * 2304;
      gemm_k<128,128,1><<<dim3(18, 18, 4), 256, 0, stream>>>(Qg, 128, 2304ll * 128, Kg, 128, 2304ll * 128,
          S4, 2304, 2304ll * 2304, 128);
      softmax16_k<<<dim3(2304, 4), 256, 0, stream>>>(S4);
      gemm_k<128,64,1><<<dim3(18, 2, 4), 256, 0, stream>>>(S4, 2304, 2304ll * 2304, Vg, 2304, 128ll * 2304,
          attn + g * 4 * 128, 2048, 128, 2304);
    }
  }

  // projections with residual + gate (8-phase, 9x16 = 144 blocks of 256x128)
  gemm9_k<128,2><<<dim3(9, 16), 512, 0, stream>>>(attn + 256 * 2048, attn, 2048, wp_i, wp_t, 2048,
      img_proj_b, txt_proj_b, img, txt, mod_i + 4096, mod_t + 4096, y1_i, y1_t, 2048, 2048);

  // LN2 + modulate
  ln_mod_k<<<2048, 256, 0, stream>>>(y1_i, mod_i + 6144, mod_i + 8192, ln2_i);
  ln_mod_k<<<256,  256, 0, stream>>>(y1_t, mod_t + 6144, mod_t + 8192, ln2_t);

  // MLP1 (GELU fused; 8-phase, 9x32 = 288 blocks of 256x256)
  gemm9_k<256,3><<<dim3(9, 32), 512, 0, stream>>>(ln2_i, ln2_t, 2048, w1_i, w1_t, 2048,
      img_mlp_b1, txt_mlp_b1, nullptr, nullptr, nullptr, nullptr, h_i, h_t, 8192, 2048);

  // MLP2 with residual + gate -> final outputs (8-phase, 9x16 = 144 blocks of 256x128)
  float* out_img = (float*)d_out;
  float* out_txt = out_img + 2048ll * 2048;
  gemm9_k<128,2><<<dim3(9, 16), 512, 0, stream>>>(h_i, h_t, 8192, w2_i, w2_t, 8192,
      img_mlp_b2, txt_mlp_b2, y1_i, y1_t, mod_i + 10240, mod_t + 10240, out_img, out_txt, 2048, 8192);
}

// Round 13
// 893.604 us; speedup vs baseline: 1.1758x; 1.1758x over previous
//
#include <hip/hip_runtime.h>

using u16 = unsigned short;
typedef __bf16 bf16x8 __attribute__((ext_vector_type(8)));
typedef float f32x4 __attribute__((ext_vector_type(4)));

__device__ inline u16 f2bf(float f){
  unsigned u = __float_as_uint(f);
  u += 0x7fff + ((u >> 16) & 1);   // RNE
  return (u16)(u >> 16);
}
__device__ inline float bf2f(u16 u){ return __uint_as_float((unsigned)u << 16); }

__device__ inline float wredsum(float v){
  #pragma unroll
  for (int o = 32; o; o >>= 1) v += __shfl_xor(v, o, 64);
  return v;
}
__device__ inline float wredmax(float v){
  #pragma unroll
  for (int o = 32; o; o >>= 1) v = fmaxf(v, __shfl_xor(v, o, 64));
  return v;
}

// direct global -> LDS DMA, 16B per lane; lds base must be wave-uniform
__device__ inline void gld16(const u16* g, u16* lds){
  __builtin_amdgcn_global_load_lds(
      (const __attribute__((address_space(1))) unsigned int*)g,
      (__attribute__((address_space(3))) unsigned int*)lds, 16, 0, 0);
}

// ---------------- mod matvec: out = silu(vec) @ W + b, W is 2048x12288 ----------------
__global__ void mod_matvec_k(const float* __restrict__ vec,
    const float* __restrict__ wi, const float* __restrict__ bi,
    const float* __restrict__ wt, const float* __restrict__ bt,
    float* __restrict__ oi, float* __restrict__ ot)
{
  __shared__ float sv[2048];
  __shared__ float red[4][64];
  int tid = threadIdx.x;
  for (int i = tid; i < 2048; i += 256){ float v = vec[i]; sv[i] = v / (1.0f + __expf(-v)); }
  __syncthreads();
  int j0 = blockIdx.x * 64;
  bool ist = j0 >= 12288;
  const float* w = ist ? wt : wi;
  const float* b = ist ? bt : bi;
  float* o = ist ? ot : oi;
  int col = (ist ? j0 - 12288 : j0) + (tid & 63);
  int kq = tid >> 6;
  float acc = 0.f;
  const float* wp = w + col;
  for (int k = kq * 512; k < kq * 512 + 512; ++k) acc += sv[k] * wp[(long long)k * 12288];
  red[kq][tid & 63] = acc;
  __syncthreads();
  if (kq == 0){
    o[col] = red[0][tid] + red[1][tid] + red[2][tid] + red[3][tid] + b[col];
  }
}

// ---------------- merged transpose + cast: 8 weights, (K x N) f32 -> (N x K) bf16 ----------------
struct TcArgs {
  const float* in[8];
  u16* out[8];
  int K[8];
  int N[8];
  int base[9];   // prefix of 32x32-tile counts
};

__global__ void tcast8_k(TcArgs a)
{
  __shared__ float tile[32][33];
  int bid = blockIdx.x;
  int w = 0;
  #pragma unroll
  for (int i = 0; i < 8; ++i) if (bid >= a.base[i + 1]) w = i + 1;
  const float* in = a.in[w];
  u16* out = a.out[w];
  int K = a.K[w], N = a.N[w];
  int local = bid - a.base[w];
  int tx = N >> 5;
  int n0 = (local % tx) * 32, k0 = (local / tx) * 32;
  int tid = threadIdx.x;
  int r = tid >> 3, c4 = (tid & 7) * 4;
  float4 v = *(const float4*)&in[(long long)(k0 + r) * N + n0 + c4];
  tile[r][c4 + 0] = v.x; tile[r][c4 + 1] = v.y; tile[r][c4 + 2] = v.z; tile[r][c4 + 3] = v.w;
  __syncthreads();
  int n = tid >> 3, kq = (tid & 7) * 4;
  ushort4 o;
  o.x = f2bf(tile[kq + 0][n]);
  o.y = f2bf(tile[kq + 1][n]);
  o.z = f2bf(tile[kq + 2][n]);
  o.w = f2bf(tile[kq + 3][n]);
  *(ushort4*)&out[(long long)(n0 + n) * K + k0 + kq] = o;
}

// ---------------- LayerNorm + modulate: out = (1+sc)*LN(x) + sh  (2048 cols) ----------------
__global__ void ln_mod_k(const float* __restrict__ x,
    const float* __restrict__ sh, const float* __restrict__ sc,
    u16* __restrict__ out)
{
  int row = blockIdx.x, tid = threadIdx.x;
  const float* xr = x + (long long)row * 2048;
  float v[8]; float s = 0.f, s2 = 0.f;
  #pragma unroll
  for (int j = 0; j < 8; ++j){ v[j] = xr[tid + j * 256]; s += v[j]; s2 += v[j] * v[j]; }
  s = wredsum(s); s2 = wredsum(s2);
  __shared__ float red[4][2];
  int wave = tid >> 6, lane = tid & 63;
  if (lane == 0){ red[wave][0] = s; red[wave][1] = s2; }
  __syncthreads();
  float S1 = red[0][0] + red[1][0] + red[2][0] + red[3][0];
  float S2 = red[0][1] + red[1][1] + red[2][1] + red[3][1];
  float mu = S1 * (1.0f / 2048.0f);
  float var = S2 * (1.0f / 2048.0f) - mu * mu;
  float rs = rsqrtf(var + 1e-6f);
  u16* orow = out + (long long)row * 2048;
  #pragma unroll
  for (int j = 0; j < 8; ++j){
    int c = tid + j * 256;
    orow[c] = f2bf((1.0f + sc[c]) * (v[j] - mu) * rs + sh[c]);
  }
}

// ---------------- QKV post: RMSNorm(q,k) + RoPE + scatter to Q/K [h][pos][d], Vt [h][d][pos] ----------------
__global__ void qkv_post_k(const float* __restrict__ qkv, int pos0,
    const float* __restrict__ qs, const float* __restrict__ ks,
    const float* __restrict__ pe,
    u16* __restrict__ Q, u16* __restrict__ Ko, u16* __restrict__ Vt)
{
  __shared__ u16 vs[128][72];
  int h = blockIdx.y;
  int t0 = blockIdx.x * 64;
  int tid = threadIdx.x, wave = tid >> 6, lane = tid & 63;
  for (int it = 0; it < 16; ++it){
    int tl = it * 4 + wave;
    int t = t0 + tl;
    const float* rp = qkv + (long long)t * 6144 + h * 128;
    float q0 = rp[lane],        q1 = rp[lane + 64];
    float k0 = rp[2048 + lane], k1 = rp[2048 + lane + 64];
    float v0 = rp[4096 + lane], v1 = rp[4096 + lane + 64];
    float qss = wredsum(q0 * q0 + q1 * q1);
    float kss = wredsum(k0 * k0 + k1 * k1);
    float rq = rsqrtf(qss * (1.0f / 128.0f) + 1e-6f) * 0.08838834764831845f; // incl 1/sqrt(DH)
    float rk = rsqrtf(kss * (1.0f / 128.0f) + 1e-6f);
    float qn0 = q0 * rq * qs[lane], qn1 = q1 * rq * qs[lane + 64];
    float kn0 = k0 * rk * ks[lane], kn1 = k1 * rk * ks[lane + 64];
    int pos = pos0 + t;
    const float* peb = pe + (long long)pos * 256;
    bool odd = lane & 1;
    float4 p0 = *(const float4*)&peb[(lane >> 1) * 4];
    float4 p1 = *(const float4*)&peb[128 + (lane >> 1) * 4];
    float c00 = odd ? p0.z : p0.x, c01 = odd ? p0.w : p0.y;
    float c10 = odd ? p1.z : p1.x, c11 = odd ? p1.w : p1.y;
    float qp0 = __shfl_xor(qn0, 1, 64), qp1 = __shfl_xor(qn1, 1, 64);
    float kp0 = __shfl_xor(kn0, 1, 64), kp1 = __shfl_xor(kn1, 1, 64);
    float qe0 = odd ? qp0 : qn0, qo0 = odd ? qn0 : qp0;
    float qe1 = odd ? qp1 : qn1, qo1 = odd ? qn1 : qp1;
    float ke0 = odd ? kp0 : kn0, ko0 = odd ? kn0 : kp0;
    float ke1 = odd ? kp1 : kn1, ko1 = odd ? kn1 : kp1;
    u16* Qr = Q  + ((long long)h * 2304 + pos) * 128;
    u16* Kr = Ko + ((long long)h * 2304 + pos) * 128;
    Qr[lane]      = f2bf(c00 * qe0 + c01 * qo0);
    Qr[lane + 64] = f2bf(c10 * qe1 + c11 * qo1);
    Kr[lane]      = f2bf(c00 * ke0 + c01 * ko0);
    Kr[lane + 64] = f2bf(c10 * ke1 + c11 * ko1);
    vs[lane][tl]      = f2bf(v0);
    vs[lane + 64][tl] = f2bf(v1);
  }
  __syncthreads();
  int dd = tid >> 1, co = (tid & 1) * 32;
  u16* vr = Vt + ((long long)h * 128 + dd) * 2304 + pos0 + t0 + co;
  #pragma unroll
  for (int u = 0; u < 8; ++u)
    *(ushort4*)(vr + u * 4) = *(const ushort4*)&vs[dd][co + u * 4];
}

// ---------------- softmax per bf16 row (2304), in-place ----------------
__global__ void softmax16_k(u16* __restrict__ S)
{
  long long base = (long long)blockIdx.y * 2304 * 2304 + (long long)blockIdx.x * 2304;
  u16* row = S + base;
  int tid = threadIdx.x;
  float v[9]; float m = -3.0e38f;
  #pragma unroll
  for (int j = 0; j < 9; ++j){ v[j] = bf2f(row[tid + j * 256]); m = fmaxf(m, v[j]); }
  m = wredmax(m);
  __shared__ float red[4];
  int wave = tid >> 6, lane = tid & 63;
  if (lane == 0) red[wave] = m;
  __syncthreads();
  m = fmaxf(fmaxf(red[0], red[1]), fmaxf(red[2], red[3]));
  float s = 0.f;
  #pragma unroll
  for (int j = 0; j < 9; ++j){ v[j] = __expf(v[j] - m); s += v[j]; }
  s = wredsum(s);
  __syncthreads();
  if (lane == 0) red[wave] = s;
  __syncthreads();
  s = red[0] + red[1] + red[2] + red[3];
  float r = 1.0f / s;
  #pragma unroll
  for (int j = 0; j < 9; ++j) row[tid + j * 256] = f2bf(v[j] * r);
}

// ---------------- split-K combine: out = res + gate[col]*(p0+p1+bias[col]) ----------------
// rows 0..2047 = img, 2048..2303 = txt (separate pointer sets). p is [z][2304][2048] f32.
__global__ void combine_k(const float* __restrict__ p, long long czoff,
    const float* __restrict__ bias_i, const float* __restrict__ bias_t,
    const float* __restrict__ res_i,  const float* __restrict__ res_t,
    const float* __restrict__ gate_i, const float* __restrict__ gate_t,
    float* __restrict__ outi, float* __restrict__ outt)
{
  int row = blockIdx.x;
  bool ist = row >= 2048;
  int r = ist ? row - 2048 : row;
  const float* bias = ist ? bias_t : bias_i;
  const float* res  = ist ? res_t  : res_i;
  const float* gate = ist ? gate_t : gate_i;
  float* out = ist ? outt : outi;
  const float* p0 = p + (long long)row * 2048;
  const float* p1 = p0 + czoff;
  long long base = (long long)r * 2048;
  int j0 = threadIdx.x * 4;
  #pragma unroll
  for (int it = 0; it < 2; ++it){
    int j = j0 + it * 1024;
    float4 a = *(const float4*)&p0[j];
    float4 b = *(const float4*)&p1[j];
    float4 bi4 = *(const float4*)&bias[j];
    float4 g = *(const float4*)&gate[j];
    float4 rr = *(const float4*)&res[base + j];
    float4 o;
    o.x = rr.x + g.x * (a.x + b.x + bi4.x);
    o.y = rr.y + g.y * (a.y + b.y + bi4.y);
    o.z = rr.z + g.z * (a.z + b.z + bi4.z);
    o.w = rr.w + g.w * (a.w + b.w + bi4.w);
    *(float4*)&out[base + j] = o;
  }
}

// ======== 8-wave depth-2 GEMM, 128x128 tile, BK=64, img+txt merged, XCD panel-chunks ========
// Blocks bx<16: img rows (M=2048); bx in [16,18): txt rows (M=256).
// XCD swizzle: s = (n%8)*(nwg/8) + n/8 (nwg/8 multiple of 18 -> complete column panels
// per XCD; B L2-resident; cut FETCH 255->208MB, R11).
// Counted vmcnt(4), raw s_barrier, 3-bit XOR-swizzled LDS (0 bank conflicts, R9),
// setprio on MFMA clusters.
// Split-K: blockIdx.z offsets A/B by z*kz (elements along K) and C by z*czoff (MODE 0).
// MODE 0: f32 = acc+bias ; 2: f32 = res + gate[col]*(acc+bias) ; 3: bf16 = gelu(acc+bias)
template<int MODE>
__global__ __launch_bounds__(512)
void gemm8_k(const u16* __restrict__ Ai, const u16* __restrict__ At, int lda,
             const u16* __restrict__ Bi, const u16* __restrict__ Bt, int ldb,
             const float* __restrict__ bias_i, const float* __restrict__ bias_t,
             const float* __restrict__ res_i,  const float* __restrict__ res_t,
             const float* __restrict__ gate_i, const float* __restrict__ gate_t,
             void* __restrict__ Ci, void* __restrict__ Ct, int ldc, int K,
             int kz, long long czoff)
{
  constexpr int BK = 64;
  constexpr int MR = 4, NR = 2;        // wave tile 64x32 (8 waves as 2M x 4N)
  constexpr int AI = 2, BI = 2;

  __shared__ u16 As[2][128 * BK];
  __shared__ u16 Bs[2][128 * BK];

  const int tid  = threadIdx.x;
  const int lane = tid & 63;
  const int wave = tid >> 6;
  const int wm = wave >> 2;            // 0..1
  const int wn = wave & 3;             // 0..3

  // XCD-aware bijective swizzle over x*y plane (z handled separately)
  const int gx = gridDim.x;
  const int nwg = gx * gridDim.y;
  const int n = blockIdx.x + gx * blockIdx.y;
  const int s_id = (n & 7) * (nwg >> 3) + (n >> 3);
  const int bx = s_id % gx;
  const int by = s_id / gx;
  const int bz = blockIdx.z;

  const bool ist = bx >= 16;
  const int rb = ist ? bx - 16 : bx;
  const u16* Ab = (ist ? At : Ai) + (long long)rb * 128 * lda + (long long)bz * kz;
  const u16* Bb = (ist ? Bt : Bi) + (long long)by * 128 * ldb + (long long)bz * kz;
  const float* bias = ist ? bias_t : bias_i;
  const float* res  = ist ? res_t  : res_i;
  const float* gate = ist ? gate_t : gate_i;
  void* C = ist ? Ct : Ci;

  // staging: instr i covers LDS rows [i*64, i*64+64); wave covers 8 rows, lane l -> row +(l>>3).
  // DMA writes linearly; global source octet pre-swizzled by (l&7)^((l>>3)&7) so that
  // LDS holds lds[row][g] = global[row][g ^ (row&7)] (involution).
  const int srow = wave * 8 + (lane >> 3);
  const int sgo  = ((lane & 7) ^ ((lane >> 3) & 7)) * 8;   // u16 units
  const u16* agp[AI]; const u16* bgp[BI];
  int alo[AI], blo[BI];
  #pragma unroll
  for (int i = 0; i < AI; ++i){
    agp[i] = Ab + (long long)(i * 64 + srow) * lda + sgo;
    alo[i] = (i * 64 + wave * 8) * BK;
  }
  #pragma unroll
  for (int i = 0; i < BI; ++i){
    bgp[i] = Bb + (long long)(i * 64 + srow) * ldb + sgo;
    blo[i] = (i * 64 + wave * 8) * BK;
  }

  const int arow0 = wm * 64;
  const int frow  = lane & 15;
  const int fx    = lane & 7;          // == row&7 for all frag rows this lane reads
  const int j0    = lane >> 4;         // base k-octet

  f32x4 acc[MR][NR] = {};

  // prologue: stage tile 0 -> buf 0 (4 vmem ops per wave)
  #pragma unroll
  for (int i = 0; i < AI; ++i) gld16(agp[i], &As[0][alo[i]]);
  #pragma unroll
  for (int i = 0; i < BI; ++i) gld16(bgp[i], &Bs[0][blo[i]]);
  __builtin_amdgcn_sched_barrier(0);

  const int nt = K / BK;
  for (int t = 0; t < nt; ++t){
    if (t + 1 < nt){
      int k0 = (t + 1) * BK;
      int nb = (t + 1) & 1;
      #pragma unroll
      for (int i = 0; i < AI; ++i) gld16(agp[i] + k0, &As[nb][alo[i]]);
      #pragma unroll
      for (int i = 0; i < BI; ++i) gld16(bgp[i] + k0, &Bs[nb][blo[i]]);
      __builtin_amdgcn_sched_barrier(0);
      // wait until only tile t+1's 4 loads remain in flight => tile t fully resident
      asm volatile("s_waitcnt vmcnt(4)" ::: "memory");
    } else {
      asm volatile("s_waitcnt vmcnt(0)" ::: "memory");
    }
    __builtin_amdgcn_sched_barrier(0);
    __builtin_amdgcn_s_barrier();                        // all waves: tile t resident
    __builtin_amdgcn_sched_barrier(0);

    const u16* as = As[t & 1];
    const u16* bs = Bs[t & 1];
    #pragma unroll
    for (int s = 0; s < 2; ++s){
      const int oct = (s * 4 + j0) ^ fx;                 // swizzled read octet
      bf16x8 bfr[NR];
      #pragma unroll
      for (int nn = 0; nn < NR; ++nn)
        bfr[nn] = *(const bf16x8*)&bs[(wn * 32 + nn * 16 + frow) * BK + oct * 8];
      __builtin_amdgcn_s_setprio(1);
      #pragma unroll
      for (int m = 0; m < MR; ++m){
        bf16x8 af = *(const bf16x8*)&as[(arow0 + m * 16 + frow) * BK + oct * 8];
        #pragma unroll
        for (int nn = 0; nn < NR; ++nn)
          acc[m][nn] = __builtin_amdgcn_mfma_f32_16x16x32_bf16(af, bfr[nn], acc[m][nn], 0, 0, 0);
      }
      __builtin_amdgcn_s_setprio(0);
    }
    __builtin_amdgcn_sched_barrier(0);
    __builtin_amdgcn_s_barrier();                        // all waves done reading buf[t&1]
    __builtin_amdgcn_sched_barrier(0);
  }

  const int lr = (lane >> 4) * 4;
  const int lc = lane & 15;
  const long long rowb = (long long)rb * 128 + arow0;
  const long long colb = (long long)by * 128 + wn * 32;
  const long long cz = (long long)bz * czoff;
  #pragma unroll
  for (int mi = 0; mi < MR; ++mi){
    #pragma unroll
    for (int ni = 0; ni < NR; ++ni){
      long long col = colb + ni * 16 + lc;
      float bv = bias ? bias[col] : 0.0f;
      #pragma unroll
      for (int j = 0; j < 4; ++j){
        long long row = rowb + mi * 16 + lr + j;
        float v = acc[mi][ni][j] + bv;
        long long ci = row * (long long)ldc + col;
        if constexpr (MODE == 0) ((float*)C)[ci + cz] = v;
        else if constexpr (MODE == 2) ((float*)C)[ci] = res[ci] + gate[col] * v;
        else {
          float z2 = 1.5957691216057308f * (v + 0.044715f * v * v * v);
          ((u16*)C)[ci] = f2bf(v / (1.0f + __expf(-z2)));
        }
      }
    }
  }
}

// ---------------- generic bf16 MFMA GEMM, 2-phase double-buffered (attention) ----------------
// MODE 0: f32 out ; 1: bf16 out
template<int BM, int BN, int MODE>
__global__ __launch_bounds__(256)
void gemm_k(const u16* __restrict__ A, int lda, long long abstr,
            const u16* __restrict__ B, int ldb, long long bbstr,
            void* __restrict__ C, int ldc, long long cbstr,
            int K)
{
  constexpr int BK  = 32;
  constexpr int WGM = BM / 64;       // waves along M (1 or 2)
  constexpr int WGN = 4 / WGM;       // waves along N
  constexpr int WTN = BN / WGN;      // wave tile N
  constexpr int NFR = WTN / 16;      // n-frags per wave
  constexpr int CA  = BM / 64;       // A staging chunks per wave (16 rows each)
  constexpr int CB  = BN / 64;       // B staging chunks per wave

  __shared__ u16 As[2][BM * BK];
  __shared__ u16 Bs[2][BN * BK];
  const int tid  = threadIdx.x;
  const int lane = tid & 63;
  const int wave = tid >> 6;
  const int wr = (wave / WGN) * 64;
  const int wc = (wave % WGN) * WTN;

  const u16* Ab = A + (long long)blockIdx.z * abstr + (long long)blockIdx.x * BM * lda;
  const u16* Bb = B + (long long)blockIdx.z * bbstr + (long long)blockIdx.y * BN * ldb;

  const int srow = lane >> 2;
  const int scol = (lane & 3) * 8;
  const u16* agp[CA]; int aro[CA];
  const u16* bgp[CB]; int bro[CB];
  #pragma unroll
  for (int c = 0; c < CA; ++c){
    int r0 = (c * 4 + wave) * 16;
    agp[c] = Ab + (long long)(r0 + srow) * lda + scol;
    aro[c] = r0 * BK;
  }
  #pragma unroll
  for (int c = 0; c < CB; ++c){
    int r0 = (c * 4 + wave) * 16;
    bgp[c] = Bb + (long long)(r0 + srow) * ldb + scol;
    bro[c] = r0 * BK;
  }

  #pragma unroll
  for (int c = 0; c < CA; ++c) gld16(agp[c], &As[0][aro[c]]);
  #pragma unroll
  for (int c = 0; c < CB; ++c) gld16(bgp[c], &Bs[0][bro[c]]);
  __syncthreads();

  f32x4 acc[4][NFR] = {};
  const int nt = K / BK;
  int cur = 0;
  for (int t = 0; t < nt; ++t){
    int nxt = cur ^ 1;
    if (t + 1 < nt){
      int ko = (t + 1) * BK;
      #pragma unroll
      for (int c = 0; c < CA; ++c) gld16(agp[c] + ko, &As[nxt][aro[c]]);
      #pragma unroll
      for (int c = 0; c < CB; ++c) gld16(bgp[c] + ko, &Bs[nxt][bro[c]]);
    }
    bf16x8 af[4], bfr[NFR];
    #pragma unroll
    for (int i = 0; i < 4; ++i)
      af[i] = *(const bf16x8*)&As[cur][(wr + i * 16 + (lane & 15)) * BK + (lane >> 4) * 8];
    #pragma unroll
    for (int i = 0; i < NFR; ++i)
      bfr[i] = *(const bf16x8*)&Bs[cur][(wc + i * 16 + (lane & 15)) * BK + (lane >> 4) * 8];
    #pragma unroll
    for (int mi = 0; mi < 4; ++mi)
      #pragma unroll
      for (int ni = 0; ni < NFR; ++ni)
        acc[mi][ni] = __builtin_amdgcn_mfma_f32_16x16x32_bf16(af[mi], bfr[ni], acc[mi][ni], 0, 0, 0);
    __syncthreads();
    cur = nxt;
  }

  const int lr = (lane >> 4) * 4;
  const int lc = lane & 15;
  const long long rowb = (long long)blockIdx.x * BM + wr;
  const long long colb = (long long)blockIdx.y * BN + wc;
  const long long cb = (long long)blockIdx.z * cbstr;
  #pragma unroll
  for (int mi = 0; mi < 4; ++mi){
    #pragma unroll
    for (int ni = 0; ni < NFR; ++ni){
      long long col = colb + ni * 16 + lc;
      #pragma unroll
      for (int j = 0; j < 4; ++j){
        long long row = rowb + mi * 16 + lr + j;
        float v = acc[mi][ni][j];
        long long ci = cb + row * ldc + col;
        if constexpr (MODE == 0) ((float*)C)[ci] = v;
        else ((u16*)C)[ci] = f2bf(v);
      }
    }
  }
}

extern "C" void kernel_launch(void* const* d_in, const int* in_sizes, int n_in,
                              void* d_out, int out_size, void* d_ws, size_t ws_size,
                              hipStream_t stream)
{
  const float* img        = (const float*)d_in[0];
  const float* txt        = (const float*)d_in[1];
  const float* vec        = (const float*)d_in[2];
  const float* img_mod_w  = (const float*)d_in[3];
  const float* img_mod_b  = (const float*)d_in[4];
  const float* txt_mod_w  = (const float*)d_in[5];
  const float* txt_mod_b  = (const float*)d_in[6];
  const float* img_qkv_w  = (const float*)d_in[7];
  const float* img_qkv_b  = (const float*)d_in[8];
  const float* img_q_s    = (const float*)d_in[9];
  const float* img_k_s    = (const float*)d_in[10];
  const float* txt_qkv_w  = (const float*)d_in[11];
  const float* txt_qkv_b  = (const float*)d_in[12];
  const float* txt_q_s    = (const float*)d_in[13];
  const float* txt_k_s    = (const float*)d_in[14];
  const float* img_proj_w = (const float*)d_in[15];
  const float* img_proj_b = (const float*)d_in[16];
  const float* txt_proj_w = (const float*)d_in[17];
  const float* txt_proj_b = (const float*)d_in[18];
  const float* img_mlp_w1 = (const float*)d_in[19];
  const float* img_mlp_b1 = (const float*)d_in[20];
  const float* img_mlp_w2 = (const float*)d_in[21];
  const float* img_mlp_b2 = (const float*)d_in[22];
  const float* txt_mlp_w1 = (const float*)d_in[23];
  const float* txt_mlp_b1 = (const float*)d_in[24];
  const float* txt_mlp_w2 = (const float*)d_in[25];
  const float* txt_mlp_b2 = (const float*)d_in[26];
  const float* pe         = (const float*)d_in[27];

  char* ws = (char*)d_ws;
  size_t off = 0;
  auto alloc = [&](size_t b){ void* p = ws + off; off = (off + b + 255) & ~(size_t)255; return p; };

  u16* wq_i = (u16*)alloc(6144ll * 2048 * 2);
  u16* wq_t = (u16*)alloc(6144ll * 2048 * 2);
  u16* wp_i = (u16*)alloc(2048ll * 2048 * 2);
  u16* wp_t = (u16*)alloc(2048ll * 2048 * 2);
  u16* w1_i = (u16*)alloc(8192ll * 2048 * 2);
  u16* w1_t = (u16*)alloc(8192ll * 2048 * 2);
  u16* w2_i = (u16*)alloc(2048ll * 8192 * 2);
  u16* w2_t = (u16*)alloc(2048ll * 8192 * 2);
  float* mod_i = (float*)alloc(12288 * 4);
  float* mod_t = (float*)alloc(12288 * 4);
  u16* Qb   = (u16*)alloc(16ll * 2304 * 128 * 2);
  u16* Kb   = (u16*)alloc(16ll * 2304 * 128 * 2);
  u16* Vt   = (u16*)alloc(16ll * 2304 * 128 * 2);
  u16* attn = (u16*)alloc(2304ll * 2048 * 2);
  float* part = (float*)alloc(2ll * 2304 * 2048 * 4);   // split-K partials (37.7 MB)
  char* big = (char*)alloc(4ll * 2304 * 2304 * 4);      // 84.9 MB reused region

  // optional merged-attention S (all 16 heads, bf16): 162 MB extra
  size_t s16_bytes = 16ll * 2304 * 2304 * 2;
  size_t off_before_s16 = off;
  u16* S16 = (u16*)alloc(s16_bytes);
  const bool merged_attn = (off <= ws_size);
  if (!merged_attn) off = off_before_s16;

  // phase 1 views
  u16*   xin_i = (u16*)big;
  u16*   xin_t = (u16*)(big + 8388608);
  float* qkv_i = (float*)(big + 9437184);
  float* qkv_t = (float*)(big + 59768832);
  // phase 2 fallback view (bf16 S for 4 heads = 42.5 MB)
  u16*   S4   = (u16*)big;
  // phase 3 views
  float* y1_i  = (float*)big;
  float* y1_t  = (float*)(big + 16777216);
  u16*   ln2_i = (u16*)(big + 18874368);
  u16*   ln2_t = (u16*)(big + 27262976);
  u16*   h_i   = (u16*)(big + 28311552);
  u16*   h_t   = (u16*)(big + 61865984);

  const long long CZ = 2304ll * 2048;   // partial z-stride
  float* pimg = part;                   // img rows 0..2047
  float* ptxt = part + 2048ll * 2048;   // txt rows (2048..2303 of merged layout)

  // modulation vectors
  mod_matvec_k<<<384, 256, 0, stream>>>(vec, img_mod_w, img_mod_b, txt_mod_w, txt_mod_b, mod_i, mod_t);

  // merged weight cast + transpose to (N x K) bf16 (1 launch instead of 8)
  {
    TcArgs a;
    const float* ins[8] = {img_qkv_w, txt_qkv_w, img_proj_w, txt_proj_w,
                           img_mlp_w1, txt_mlp_w1, img_mlp_w2, txt_mlp_w2};
    u16* outs[8] = {wq_i, wq_t, wp_i, wp_t, w1_i, w1_t, w2_i, w2_t};
    int Ks[8] = {2048, 2048, 2048, 2048, 2048, 2048, 8192, 8192};
    int Ns[8] = {6144, 6144, 2048, 2048, 8192, 8192, 2048, 2048};
    int b = 0;
    for (int i = 0; i < 8; ++i){
      a.in[i] = ins[i]; a.out[i] = outs[i]; a.K[i] = Ks[i]; a.N[i] = Ns[i];
      a.base[i] = b;
      b += (Ks[i] >> 5) * (Ns[i] >> 5);
    }
    a.base[8] = b;
    tcast8_k<<<b, 256, 0, stream>>>(a);
  }

  // LN1 + modulate
  ln_mod_k<<<2048, 256, 0, stream>>>(img, mod_i, mod_i + 2048, xin_i);
  ln_mod_k<<<256,  256, 0, stream>>>(txt, mod_t, mod_t + 2048, xin_t);

  // QKV GEMM (img+txt merged: 18x48 = 864 blocks)
  gemm8_k<0><<<dim3(18, 48), 512, 0, stream>>>(xin_i, xin_t, 2048, wq_i, wq_t, 2048,
      img_qkv_b, txt_qkv_b, nullptr, nullptr, nullptr, nullptr, qkv_i, qkv_t, 6144, 2048, 0, 0);

  // RMSNorm + RoPE + scatter (txt occupies positions 0..255, img 256..2303)
  qkv_post_k<<<dim3(32, 16), 256, 0, stream>>>(qkv_i, 256, img_q_s, img_k_s, pe, Qb, Kb, Vt);
  qkv_post_k<<<dim3(4, 16),  256, 0, stream>>>(qkv_t, 0,   txt_q_s, txt_k_s, pe, Qb, Kb, Vt);

  // attention: QK^T (bf16 S) -> softmax -> PV
  if (merged_attn){
    gemm_k<128,128,1><<<dim3(18, 18, 16), 256, 0, stream>>>(Qb, 128, 2304ll * 128, Kb, 128, 2304ll * 128,
        S16, 2304, 2304ll * 2304, 128);
    softmax16_k<<<dim3(2304, 16), 256, 0, stream>>>(S16);
    gemm_k<128,64,1><<<dim3(18, 2, 16), 256, 0, stream>>>(S16, 2304, 2304ll * 2304, Vt, 2304, 128ll * 2304,
        attn, 2048, 128, 2304);
  } else {
    for (int g = 0; g < 4; ++g){
      const u16* Qg = Qb + (long long)g * 4 * 2304 * 128;
      const u16* Kg = Kb + (long long)g * 4 * 2304 * 128;
      const u16* Vg = Vt + (long long)g * 4 * 128 * 2304;
      gemm_k<128,128,1><<<dim3(18, 18, 4), 256, 0, stream>>>(Qg, 128, 2304ll * 128, Kg, 128, 2304ll * 128,
          S4, 2304, 2304ll * 2304, 128);
      softmax16_k<<<dim3(2304, 4), 256, 0, stream>>>(S4);
      gemm_k<128,64,1><<<dim3(18, 2, 4), 256, 0, stream>>>(S4, 2304, 2304ll * 2304, Vg, 2304, 128ll * 2304,
          attn + g * 4 * 128, 2048, 128, 2304);
    }
  }

  // projection: split-K=2 (18x16x2 = 576 blocks) -> partials -> combine (res+gate+bias)
  gemm8_k<0><<<dim3(18, 16, 2), 512, 0, stream>>>(attn + 256 * 2048, attn, 2048, wp_i, wp_t, 2048,
      nullptr, nullptr, nullptr, nullptr, nullptr, nullptr, pimg, ptxt, 2048, 1024, 1024, CZ);
  combine_k<<<2304, 256, 0, stream>>>(part, CZ, img_proj_b, txt_proj_b, img, txt,
      mod_i + 4096, mod_t + 4096, y1_i, y1_t);

  // LN2 + modulate
  ln_mod_k<<<2048, 256, 0, stream>>>(y1_i, mod_i + 6144, mod_i + 8192, ln2_i);
  ln_mod_k<<<256,  256, 0, stream>>>(y1_t, mod_t + 6144, mod_t + 8192, ln2_t);

  // MLP1 (GELU fused; merged: 18x64 = 1152 blocks)
  gemm8_k<3><<<dim3(18, 64), 512, 0, stream>>>(ln2_i, ln2_t, 2048, w1_i, w1_t, 2048,
      img_mlp_b1, txt_mlp_b1, nullptr, nullptr, nullptr, nullptr, h_i, h_t, 8192, 2048, 0, 0);

  // MLP2: split-K=2 (18x16x2 = 576 blocks) -> partials -> combine -> final outputs
  float* out_img = (float*)d_out;
  float* out_txt = out_img + 2048ll * 2048;
  gemm8_k<0><<<dim3(18, 16, 2), 512, 0, stream>>>(h_i, h_t, 8192, w2_i, w2_t, 8192,
      nullptr, nullptr, nullptr, nullptr, nullptr, nullptr, pimg, ptxt, 2048, 4096, 4096, CZ);
  combine_k<<<2304, 256, 0, stream>>>(part, CZ, img_mlp_b2, txt_mlp_b2, y1_i, y1_t,
      mod_i + 10240, mod_t + 10240, out_img, out_txt);
}

// Round 14
// 863.171 us; speedup vs baseline: 1.2173x; 1.0353x over previous
//
#include <hip/hip_runtime.h>

using u16 = unsigned short;
typedef __bf16 bf16x8 __attribute__((ext_vector_type(8)));
typedef float f32x4 __attribute__((ext_vector_type(4)));

__device__ inline u16 f2bf(float f){
  unsigned u = __float_as_uint(f);
  u += 0x7fff + ((u >> 16) & 1);   // RNE
  return (u16)(u >> 16);
}

__device__ inline float wredsum(float v){
  #pragma unroll
  for (int o = 32; o; o >>= 1) v += __shfl_xor(v, o, 64);
  return v;
}

// direct global -> LDS DMA, 16B per lane; lds base must be wave-uniform
__device__ inline void gld16(const u16* g, u16* lds){
  __builtin_amdgcn_global_load_lds(
      (const __attribute__((address_space(1))) unsigned int*)g,
      (__attribute__((address_space(3))) unsigned int*)lds, 16, 0, 0);
}

// ---------------- mod matvec: out = silu(vec) @ W + b, W is 2048x12288 ----------------
__global__ void mod_matvec_k(const float* __restrict__ vec,
    const float* __restrict__ wi, const float* __restrict__ bi,
    const float* __restrict__ wt, const float* __restrict__ bt,
    float* __restrict__ oi, float* __restrict__ ot)
{
  __shared__ float sv[2048];
  __shared__ float red[4][64];
  int tid = threadIdx.x;
  for (int i = tid; i < 2048; i += 256){ float v = vec[i]; sv[i] = v / (1.0f + __expf(-v)); }
  __syncthreads();
  int j0 = blockIdx.x * 64;
  bool ist = j0 >= 12288;
  const float* w = ist ? wt : wi;
  const float* b = ist ? bt : bi;
  float* o = ist ? ot : oi;
  int col = (ist ? j0 - 12288 : j0) + (tid & 63);
  int kq = tid >> 6;
  float acc = 0.f;
  const float* wp = w + col;
  for (int k = kq * 512; k < kq * 512 + 512; ++k) acc += sv[k] * wp[(long long)k * 12288];
  red[kq][tid & 63] = acc;
  __syncthreads();
  if (kq == 0){
    o[col] = red[0][tid] + red[1][tid] + red[2][tid] + red[3][tid] + b[col];
  }
}

// ---------------- merged transpose + cast: 8 weights, (K x N) f32 -> (N x K) bf16 ----------------
struct TcArgs {
  const float* in[8];
  u16* out[8];
  int K[8];
  int N[8];
  int base[9];   // prefix of 32x32-tile counts
};

__global__ void tcast8_k(TcArgs a)
{
  __shared__ float tile[32][33];
  int bid = blockIdx.x;
  int w = 0;
  #pragma unroll
  for (int i = 0; i < 8; ++i) if (bid >= a.base[i + 1]) w = i + 1;
  const float* in = a.in[w];
  u16* out = a.out[w];
  int K = a.K[w], N = a.N[w];
  int local = bid - a.base[w];
  int tx = N >> 5;
  int n0 = (local % tx) * 32, k0 = (local / tx) * 32;
  int tid = threadIdx.x;
  int r = tid >> 3, c4 = (tid & 7) * 4;
  float4 v = *(const float4*)&in[(long long)(k0 + r) * N + n0 + c4];
  tile[r][c4 + 0] = v.x; tile[r][c4 + 1] = v.y; tile[r][c4 + 2] = v.z; tile[r][c4 + 3] = v.w;
  __syncthreads();
  int n = tid >> 3, kq = (tid & 7) * 4;
  ushort4 o;
  o.x = f2bf(tile[kq + 0][n]);
  o.y = f2bf(tile[kq + 1][n]);
  o.z = f2bf(tile[kq + 2][n]);
  o.w = f2bf(tile[kq + 3][n]);
  *(ushort4*)&out[(long long)(n0 + n) * K + k0 + kq] = o;
}

// ---------------- LayerNorm + modulate: out = (1+sc)*LN(x) + sh  (2048 cols) ----------------
__global__ void ln_mod_k(const float* __restrict__ x,
    const float* __restrict__ sh, const float* __restrict__ sc,
    u16* __restrict__ out)
{
  int row = blockIdx.x, tid = threadIdx.x;
  const float* xr = x + (long long)row * 2048;
  float v[8]; float s = 0.f, s2 = 0.f;
  #pragma unroll
  for (int j = 0; j < 8; ++j){ v[j] = xr[tid + j * 256]; s += v[j]; s2 += v[j] * v[j]; }
  s = wredsum(s); s2 = wredsum(s2);
  __shared__ float red[4][2];
  int wave = tid >> 6, lane = tid & 63;
  if (lane == 0){ red[wave][0] = s; red[wave][1] = s2; }
  __syncthreads();
  float S1 = red[0][0] + red[1][0] + red[2][0] + red[3][0];
  float S2 = red[0][1] + red[1][1] + red[2][1] + red[3][1];
  float mu = S1 * (1.0f / 2048.0f);
  float var = S2 * (1.0f / 2048.0f) - mu * mu;
  float rs = rsqrtf(var + 1e-6f);
  u16* orow = out + (long long)row * 2048;
  #pragma unroll
  for (int j = 0; j < 8; ++j){
    int c = tid + j * 256;
    orow[c] = f2bf((1.0f + sc[c]) * (v[j] - mu) * rs + sh[c]);
  }
}

// ---------------- QKV post: RMSNorm(q,k) + RoPE + scatter to Q/K [h][pos][d], Vt [h][d][pos] ----------------
__global__ void qkv_post_k(const float* __restrict__ qkv, int pos0,
    const float* __restrict__ qs, const float* __restrict__ ks,
    const float* __restrict__ pe,
    u16* __restrict__ Q, u16* __restrict__ Ko, u16* __restrict__ Vt)
{
  __shared__ u16 vs[128][72];
  int h = blockIdx.y;
  int t0 = blockIdx.x * 64;
  int tid = threadIdx.x, wave = tid >> 6, lane = tid & 63;
  for (int it = 0; it < 16; ++it){
    int tl = it * 4 + wave;
    int t = t0 + tl;
    const float* rp = qkv + (long long)t * 6144 + h * 128;
    float q0 = rp[lane],        q1 = rp[lane + 64];
    float k0 = rp[2048 + lane], k1 = rp[2048 + lane + 64];
    float v0 = rp[4096 + lane], v1 = rp[4096 + lane + 64];
    float qss = wredsum(q0 * q0 + q1 * q1);
    float kss = wredsum(k0 * k0 + k1 * k1);
    float rq = rsqrtf(qss * (1.0f / 128.0f) + 1e-6f) * 0.08838834764831845f; // incl 1/sqrt(DH)
    float rk = rsqrtf(kss * (1.0f / 128.0f) + 1e-6f);
    float qn0 = q0 * rq * qs[lane], qn1 = q1 * rq * qs[lane + 64];
    float kn0 = k0 * rk * ks[lane], kn1 = k1 * rk * ks[lane + 64];
    int pos = pos0 + t;
    const float* peb = pe + (long long)pos * 256;
    bool odd = lane & 1;
    float4 p0 = *(const float4*)&peb[(lane >> 1) * 4];
    float4 p1 = *(const float4*)&peb[128 + (lane >> 1) * 4];
    float c00 = odd ? p0.z : p0.x, c01 = odd ? p0.w : p0.y;
    float c10 = odd ? p1.z : p1.x, c11 = odd ? p1.w : p1.y;
    float qp0 = __shfl_xor(qn0, 1, 64), qp1 = __shfl_xor(qn1, 1, 64);
    float kp0 = __shfl_xor(kn0, 1, 64), kp1 = __shfl_xor(kn1, 1, 64);
    float qe0 = odd ? qp0 : qn0, qo0 = odd ? qn0 : qp0;
    float qe1 = odd ? qp1 : qn1, qo1 = odd ? qn1 : qp1;
    float ke0 = odd ? kp0 : kn0, ko0 = odd ? kn0 : kp0;
    float ke1 = odd ? kp1 : kn1, ko1 = odd ? kn1 : kp1;
    u16* Qr = Q  + ((long long)h * 2304 + pos) * 128;
    u16* Kr = Ko + ((long long)h * 2304 + pos) * 128;
    Qr[lane]      = f2bf(c00 * qe0 + c01 * qo0);
    Qr[lane + 64] = f2bf(c10 * qe1 + c11 * qo1);
    Kr[lane]      = f2bf(c00 * ke0 + c01 * ko0);
    Kr[lane + 64] = f2bf(c10 * ke1 + c11 * ko1);
    vs[lane][tl]      = f2bf(v0);
    vs[lane + 64][tl] = f2bf(v1);
  }
  __syncthreads();
  int dd = tid >> 1, co = (tid & 1) * 32;
  u16* vr = Vt + ((long long)h * 128 + dd) * 2304 + pos0 + t0 + co;
  #pragma unroll
  for (int u = 0; u < 8; ++u)
    *(ushort4*)(vr + u * 4) = *(const ushort4*)&vs[dd][co + u * 4];
}

// ======== fused flash attention: grid (18 q-blocks, 16 heads), 8 waves ========
// Per block: Q-tile A-frags in regs; loop 18 kv-tiles: stage K,V (gld16, src-swizzled);
// QK^T with wave tile 16x128 (each row whole within one wave -> intra-wave row stats);
// online softmax (f32); P bf16 -> freed Q-LDS (XOR-swizzled, intra-wave); PV accumulates O.
// V double-buffered so K(t+1),V(t+1) stages issue right after QK^T barrier and hide
// under softmax+PV. 2 barriers/tile. LDS = 32(P) + 32(K) + 64(V) = 128 KB.
__global__ __launch_bounds__(512)
void fattn_k(const u16* __restrict__ Qb, const u16* __restrict__ Kb,
             const u16* __restrict__ Vt, u16* __restrict__ attn)
{
  __shared__ u16 Pl[128 * 128];      // Q staging first, then P
  __shared__ u16 Kl[128 * 128];
  __shared__ u16 Vl[2][128 * 128];

  const int tid  = threadIdx.x;
  const int lane = tid & 63;
  const int wave = tid >> 6;
  const int h  = blockIdx.y;
  const int q0 = blockIdx.x * 128;

  const u16* Qg = Qb + ((long long)h * 2304 + q0) * 128;
  const u16* Kg = Kb + (long long)h * 2304 * 128;
  const u16* Vg = Vt + (long long)h * 128 * 2304;

  // stage a 128x128 u16 tile: instr i covers rows [i*32,i*32+32); wave covers 4 rows,
  // lane l -> row +(l>>4), dest octet l&15 (linear). Source octet ^ (row&7) so LDS
  // holds lds[r][o] = glob[r][o ^ (r&7)] (involution; conflict-free b128 reads).
  const int s_r   = wave * 4 + (lane >> 4);
  const int s_oct = lane & 15;
  auto stage = [&](const u16* g, int ldg, u16* lds){
    #pragma unroll
    for (int i = 0; i < 4; ++i){
      int row = i * 32 + s_r;
      gld16(g + (long long)row * ldg + ((s_oct ^ (row & 7)) * 8),
            lds + (i * 32 + wave * 4) * 128);
    }
  };

  // prologue: Q -> Pl, K0 -> Kl, V0 -> Vl[0]
  stage(Qg, 128, Pl);
  stage(Kg, 128, Kl);
  stage(Vg, 2304, Vl[0]);
  __syncthreads();                   // all resident

  // hoist Q A-frags to regs: row = wave*16 + (lane&15), oct (s*4 + (lane>>4)) ^ (row&7)
  const int frow = lane & 15;
  const int j0   = lane >> 4;
  const int qrow = wave * 16 + frow;
  bf16x8 aq[4];
  #pragma unroll
  for (int s = 0; s < 4; ++s)
    aq[s] = *(const bf16x8*)&Pl[qrow * 128 + (((s * 4 + j0) ^ (qrow & 7)) * 8)];
  __syncthreads();                   // Q reads done; Pl free for P

  float mrun[4], lrun[4];
  #pragma unroll
  for (int j = 0; j < 4; ++j){ mrun[j] = -3.0e38f; lrun[j] = 0.f; }
  f32x4 oacc[8] = {};

  for (int t = 0; t < 18; ++t){
    asm volatile("s_waitcnt vmcnt(0)" ::: "memory");   // K(t),V(t) resident
    __builtin_amdgcn_sched_barrier(0);
    __builtin_amdgcn_s_barrier();
    __builtin_amdgcn_sched_barrier(0);

    // QK^T: S[wave's 16 rows][128 kv]
    f32x4 sacc[8] = {};
    #pragma unroll
    for (int s = 0; s < 4; ++s){
      #pragma unroll
      for (int n = 0; n < 8; ++n){
        int kr = n * 16 + frow;
        bf16x8 bk = *(const bf16x8*)&Kl[kr * 128 + (((s * 4 + j0) ^ (kr & 7)) * 8)];
        sacc[n] = __builtin_amdgcn_mfma_f32_16x16x32_bf16(aq[s], bk, sacc[n], 0, 0, 0);
      }
    }
    __builtin_amdgcn_sched_barrier(0);
    __builtin_amdgcn_s_barrier();                      // all waves done reading Kl
    __builtin_amdgcn_sched_barrier(0);
    if (t + 1 < 18){
      stage(Kg + (long long)(t + 1) * 128 * 128, 128, Kl);
      stage(Vg + (t + 1) * 128, 2304, Vl[(t + 1) & 1]);
    }
    __builtin_amdgcn_sched_barrier(0);

    // online softmax; thread rows r(j) = wave*16 + j0*4 + j, cols n*16+frow
    float mnew[4], scl[4];
    #pragma unroll
    for (int j = 0; j < 4; ++j){
      float v = sacc[0][j];
      #pragma unroll
      for (int n = 1; n < 8; ++n) v = fmaxf(v, sacc[n][j]);
      #pragma unroll
      for (int o = 8; o; o >>= 1) v = fmaxf(v, __shfl_xor(v, o, 64));
      mnew[j] = fmaxf(mrun[j], v);
      scl[j] = __expf(mrun[j] - mnew[j]);
      mrun[j] = mnew[j];
    }
    #pragma unroll
    for (int j = 0; j < 4; ++j){
      const int row = wave * 16 + j0 * 4 + j;
      float rsum = 0.f;
      #pragma unroll
      for (int n = 0; n < 8; ++n){
        float p = __expf(sacc[n][j] - mnew[j]);
        rsum += p;
        int col = n * 16 + frow;
        Pl[row * 128 + (((col >> 3) ^ (row & 7)) << 3) + (col & 7)] = f2bf(p);
      }
      #pragma unroll
      for (int o = 8; o; o >>= 1) rsum += __shfl_xor(rsum, o, 64);
      lrun[j] = lrun[j] * scl[j] + rsum;
      #pragma unroll
      for (int n = 0; n < 8; ++n) oacc[n][j] *= scl[j];
    }
    asm volatile("s_waitcnt lgkmcnt(0)" ::: "memory"); // P writes retired (intra-wave)
    __builtin_amdgcn_sched_barrier(0);

    // PV: O[wave rows][d] += P * V^T  (V resident since top barrier)
    const u16* vl = Vl[t & 1];
    #pragma unroll
    for (int s = 0; s < 4; ++s){
      bf16x8 ap = *(const bf16x8*)&Pl[qrow * 128 + (((s * 4 + j0) ^ (qrow & 7)) * 8)];
      #pragma unroll
      for (int n = 0; n < 8; ++n){
        int dr = n * 16 + frow;
        bf16x8 bv = *(const bf16x8*)&vl[dr * 128 + (((s * 4 + j0) ^ (dr & 7)) * 8)];
        oacc[n] = __builtin_amdgcn_mfma_f32_16x16x32_bf16(ap, bv, oacc[n], 0, 0, 0);
      }
    }
    __builtin_amdgcn_sched_barrier(0);
  }

  // epilogue: O/l -> attn[(q0+row)][h*128 + d]
  float inv[4];
  #pragma unroll
  for (int j = 0; j < 4; ++j) inv[j] = 1.0f / lrun[j];
  #pragma unroll
  for (int n = 0; n < 8; ++n){
    int d = n * 16 + frow;
    #pragma unroll
    for (int j = 0; j < 4; ++j){
      int row = wave * 16 + j0 * 4 + j;
      attn[(long long)(q0 + row) * 2048 + h * 128 + d] = f2bf(oacc[n][j] * inv[j]);
    }
  }
}

// ======== 8-wave depth-2 GEMM, 128x128 tile, BK=64, img+txt merged, XCD panel-chunks ========
// Blocks bx<16: img rows (M=2048); bx in [16,18): txt rows (M=256).
// XCD swizzle: s = (n%8)*(nwg/8) + n/8 (nwg/8 multiple of 18 -> complete column panels
// per XCD; B L2-resident; cut FETCH 255->208MB, R11).
// Counted vmcnt(4), raw s_barrier, 3-bit XOR-swizzled LDS (0 bank conflicts, R9),
// setprio on MFMA clusters.
// MODE 0: f32 = acc+bias ; 2: f32 = res + gate[col]*(acc+bias) ; 3: bf16 = gelu(acc+bias)
template<int MODE>
__global__ __launch_bounds__(512)
void gemm8_k(const u16* __restrict__ Ai, const u16* __restrict__ At, int lda,
             const u16* __restrict__ Bi, const u16* __restrict__ Bt, int ldb,
             const float* __restrict__ bias_i, const float* __restrict__ bias_t,
             const float* __restrict__ res_i,  const float* __restrict__ res_t,
             const float* __restrict__ gate_i, const float* __restrict__ gate_t,
             void* __restrict__ Ci, void* __restrict__ Ct, int ldc, int K)
{
  constexpr int BK = 64;
  constexpr int MR = 4, NR = 2;        // wave tile 64x32 (8 waves as 2M x 4N)
  constexpr int AI = 2, BI = 2;

  __shared__ u16 As[2][128 * BK];
  __shared__ u16 Bs[2][128 * BK];

  const int tid  = threadIdx.x;
  const int lane = tid & 63;
  const int wave = tid >> 6;
  const int wm = wave >> 2;            // 0..1
  const int wn = wave & 3;             // 0..3

  const int gx = gridDim.x;
  const int nwg = gx * gridDim.y;
  const int n = blockIdx.x + gx * blockIdx.y;
  const int s_id = (n & 7) * (nwg >> 3) + (n >> 3);
  const int bx = s_id % gx;
  const int by = s_id / gx;

  const bool ist = bx >= 16;
  const int rb = ist ? bx - 16 : bx;
  const u16* Ab = (ist ? At : Ai) + (long long)rb * 128 * lda;
  const u16* Bb = (ist ? Bt : Bi) + (long long)by * 128 * ldb;
  const float* bias = ist ? bias_t : bias_i;
  const float* res  = ist ? res_t  : res_i;
  const float* gate = ist ? gate_t : gate_i;
  void* C = ist ? Ct : Ci;

  const int srow = wave * 8 + (lane >> 3);
  const int sgo  = ((lane & 7) ^ ((lane >> 3) & 7)) * 8;   // u16 units
  const u16* agp[AI]; const u16* bgp[BI];
  int alo[AI], blo[BI];
  #pragma unroll
  for (int i = 0; i < AI; ++i){
    agp[i] = Ab + (long long)(i * 64 + srow) * lda + sgo;
    alo[i] = (i * 64 + wave * 8) * BK;
  }
  #pragma unroll
  for (int i = 0; i < BI; ++i){
    bgp[i] = Bb + (long long)(i * 64 + srow) * ldb + sgo;
    blo[i] = (i * 64 + wave * 8) * BK;
  }

  const int arow0 = wm * 64;
  const int frow  = lane & 15;
  const int fx    = lane & 7;
  const int j0    = lane >> 4;

  f32x4 acc[MR][NR] = {};

  #pragma unroll
  for (int i = 0; i < AI; ++i) gld16(agp[i], &As[0][alo[i]]);
  #pragma unroll
  for (int i = 0; i < BI; ++i) gld16(bgp[i], &Bs[0][blo[i]]);
  __builtin_amdgcn_sched_barrier(0);

  const int nt = K / BK;
  for (int t = 0; t < nt; ++t){
    if (t + 1 < nt){
      int k0 = (t + 1) * BK;
      int nb = (t + 1) & 1;
      #pragma unroll
      for (int i = 0; i < AI; ++i) gld16(agp[i] + k0, &As[nb][alo[i]]);
      #pragma unroll
      for (int i = 0; i < BI; ++i) gld16(bgp[i] + k0, &Bs[nb][blo[i]]);
      __builtin_amdgcn_sched_barrier(0);
      asm volatile("s_waitcnt vmcnt(4)" ::: "memory");
    } else {
      asm volatile("s_waitcnt vmcnt(0)" ::: "memory");
    }
    __builtin_amdgcn_sched_barrier(0);
    __builtin_amdgcn_s_barrier();
    __builtin_amdgcn_sched_barrier(0);

    const u16* as = As[t & 1];
    const u16* bs = Bs[t & 1];
    #pragma unroll
    for (int s = 0; s < 2; ++s){
      const int oct = (s * 4 + j0) ^ fx;
      bf16x8 bfr[NR];
      #pragma unroll
      for (int nn = 0; nn < NR; ++nn)
        bfr[nn] = *(const bf16x8*)&bs[(wn * 32 + nn * 16 + frow) * BK + oct * 8];
      __builtin_amdgcn_s_setprio(1);
      #pragma unroll
      for (int m = 0; m < MR; ++m){
        bf16x8 af = *(const bf16x8*)&as[(arow0 + m * 16 + frow) * BK + oct * 8];
        #pragma unroll
        for (int nn = 0; nn < NR; ++nn)
          acc[m][nn] = __builtin_amdgcn_mfma_f32_16x16x32_bf16(af, bfr[nn], acc[m][nn], 0, 0, 0);
      }
      __builtin_amdgcn_s_setprio(0);
    }
    __builtin_amdgcn_sched_barrier(0);
    __builtin_amdgcn_s_barrier();
    __builtin_amdgcn_sched_barrier(0);
  }

  const int lr = (lane >> 4) * 4;
  const int lc = lane & 15;
  const long long rowb = (long long)rb * 128 + arow0;
  const long long colb = (long long)by * 128 + wn * 32;
  #pragma unroll
  for (int mi = 0; mi < MR; ++mi){
    #pragma unroll
    for (int ni = 0; ni < NR; ++ni){
      long long col = colb + ni * 16 + lc;
      float bv = bias ? bias[col] : 0.0f;
      #pragma unroll
      for (int j = 0; j < 4; ++j){
        long long row = rowb + mi * 16 + lr + j;
        float v = acc[mi][ni][j] + bv;
        long long ci = row * (long long)ldc + col;
        if constexpr (MODE == 0) ((float*)C)[ci] = v;
        else if constexpr (MODE == 2) ((float*)C)[ci] = res[ci] + gate[col] * v;
        else {
          float z2 = 1.5957691216057308f * (v + 0.044715f * v * v * v);
          ((u16*)C)[ci] = f2bf(v / (1.0f + __expf(-z2)));
        }
      }
    }
  }
}

extern "C" void kernel_launch(void* const* d_in, const int* in_sizes, int n_in,
                              void* d_out, int out_size, void* d_ws, size_t ws_size,
                              hipStream_t stream)
{
  const float* img        = (const float*)d_in[0];
  const float* txt        = (const float*)d_in[1];
  const float* vec        = (const float*)d_in[2];
  const float* img_mod_w  = (const float*)d_in[3];
  const float* img_mod_b  = (const float*)d_in[4];
  const float* txt_mod_w  = (const float*)d_in[5];
  const float* txt_mod_b  = (const float*)d_in[6];
  const float* img_qkv_w  = (const float*)d_in[7];
  const float* img_qkv_b  = (const float*)d_in[8];
  const float* img_q_s    = (const float*)d_in[9];
  const float* img_k_s    = (const float*)d_in[10];
  const float* txt_qkv_w  = (const float*)d_in[11];
  const float* txt_qkv_b  = (const float*)d_in[12];
  const float* txt_q_s    = (const float*)d_in[13];
  const float* txt_k_s    = (const float*)d_in[14];
  const float* img_proj_w = (const float*)d_in[15];
  const float* img_proj_b = (const float*)d_in[16];
  const float* txt_proj_w = (const float*)d_in[17];
  const float* txt_proj_b = (const float*)d_in[18];
  const float* img_mlp_w1 = (const float*)d_in[19];
  const float* img_mlp_b1 = (const float*)d_in[20];
  const float* img_mlp_w2 = (const float*)d_in[21];
  const float* img_mlp_b2 = (const float*)d_in[22];
  const float* txt_mlp_w1 = (const float*)d_in[23];
  const float* txt_mlp_b1 = (const float*)d_in[24];
  const float* txt_mlp_w2 = (const float*)d_in[25];
  const float* txt_mlp_b2 = (const float*)d_in[26];
  const float* pe         = (const float*)d_in[27];

  char* ws = (char*)d_ws;
  size_t off = 0;
  auto alloc = [&](size_t b){ void* p = ws + off; off = (off + b + 255) & ~(size_t)255; return p; };

  u16* wq_i = (u16*)alloc(6144ll * 2048 * 2);
  u16* wq_t = (u16*)alloc(6144ll * 2048 * 2);
  u16* wp_i = (u16*)alloc(2048ll * 2048 * 2);
  u16* wp_t = (u16*)alloc(2048ll * 2048 * 2);
  u16* w1_i = (u16*)alloc(8192ll * 2048 * 2);
  u16* w1_t = (u16*)alloc(8192ll * 2048 * 2);
  u16* w2_i = (u16*)alloc(2048ll * 8192 * 2);
  u16* w2_t = (u16*)alloc(2048ll * 8192 * 2);
  float* mod_i = (float*)alloc(12288 * 4);
  float* mod_t = (float*)alloc(12288 * 4);
  u16* Qb   = (u16*)alloc(16ll * 2304 * 128 * 2);
  u16* Kb   = (u16*)alloc(16ll * 2304 * 128 * 2);
  u16* Vt   = (u16*)alloc(16ll * 2304 * 128 * 2);
  u16* attn = (u16*)alloc(2304ll * 2048 * 2);
  char* big = (char*)alloc(4ll * 2304 * 2304 * 4);   // 84.9 MB reused region

  // phase 1 views
  u16*   xin_i = (u16*)big;
  u16*   xin_t = (u16*)(big + 8388608);
  float* qkv_i = (float*)(big + 9437184);
  float* qkv_t = (float*)(big + 59768832);
  // phase 3 views
  float* y1_i  = (float*)big;
  float* y1_t  = (float*)(big + 16777216);
  u16*   ln2_i = (u16*)(big + 18874368);
  u16*   ln2_t = (u16*)(big + 27262976);
  u16*   h_i   = (u16*)(big + 28311552);
  u16*   h_t   = (u16*)(big + 61865984);

  // modulation vectors
  mod_matvec_k<<<384, 256, 0, stream>>>(vec, img_mod_w, img_mod_b, txt_mod_w, txt_mod_b, mod_i, mod_t);

  // merged weight cast + transpose to (N x K) bf16
  {
    TcArgs a;
    const float* ins[8] = {img_qkv_w, txt_qkv_w, img_proj_w, txt_proj_w,
                           img_mlp_w1, txt_mlp_w1, img_mlp_w2, txt_mlp_w2};
    u16* outs[8] = {wq_i, wq_t, wp_i, wp_t, w1_i, w1_t, w2_i, w2_t};
    int Ks[8] = {2048, 2048, 2048, 2048, 2048, 2048, 8192, 8192};
    int Ns[8] = {6144, 6144, 2048, 2048, 8192, 8192, 2048, 2048};
    int b = 0;
    for (int i = 0; i < 8; ++i){
      a.in[i] = ins[i]; a.out[i] = outs[i]; a.K[i] = Ks[i]; a.N[i] = Ns[i];
      a.base[i] = b;
      b += (Ks[i] >> 5) * (Ns[i] >> 5);
    }
    a.base[8] = b;
    tcast8_k<<<b, 256, 0, stream>>>(a);
  }

  // LN1 + modulate
  ln_mod_k<<<2048, 256, 0, stream>>>(img, mod_i, mod_i + 2048, xin_i);
  ln_mod_k<<<256,  256, 0, stream>>>(txt, mod_t, mod_t + 2048, xin_t);

  // QKV GEMM (img+txt merged: 18x48 = 864 blocks)
  gemm8_k<0><<<dim3(18, 48), 512, 0, stream>>>(xin_i, xin_t, 2048, wq_i, wq_t, 2048,
      img_qkv_b, txt_qkv_b, nullptr, nullptr, nullptr, nullptr, qkv_i, qkv_t, 6144, 2048);

  // RMSNorm + RoPE + scatter (txt occupies positions 0..255, img 256..2303)
  qkv_post_k<<<dim3(32, 16), 256, 0, stream>>>(qkv_i, 256, img_q_s, img_k_s, pe, Qb, Kb, Vt);
  qkv_post_k<<<dim3(4, 16),  256, 0, stream>>>(qkv_t, 0,   txt_q_s, txt_k_s, pe, Qb, Kb, Vt);

  // fused flash attention (one launch)
  fattn_k<<<dim3(18, 16), 512, 0, stream>>>(Qb, Kb, Vt, attn);

  // projections with residual + gate (merged: 18x16 = 288 blocks)
  gemm8_k<2><<<dim3(18, 16), 512, 0, stream>>>(attn + 256 * 2048, attn, 2048, wp_i, wp_t, 2048,
      img_proj_b, txt_proj_b, img, txt, mod_i + 4096, mod_t + 4096, y1_i, y1_t, 2048, 2048);

  // LN2 + modulate
  ln_mod_k<<<2048, 256, 0, stream>>>(y1_i, mod_i + 6144, mod_i + 8192, ln2_i);
  ln_mod_k<<<256,  256, 0, stream>>>(y1_t, mod_t + 6144, mod_t + 8192, ln2_t);

  // MLP1 (GELU fused; merged: 18x64 = 1152 blocks)
  gemm8_k<3><<<dim3(18, 64), 512, 0, stream>>>(ln2_i, ln2_t, 2048, w1_i, w1_t, 2048,
      img_mlp_b1, txt_mlp_b1, nullptr, nullptr, nullptr, nullptr, h_i, h_t, 8192, 2048);

  // MLP2 with residual + gate -> final outputs (merged: 18x16 = 288 blocks)
  float* out_img = (float*)d_out;
  float* out_txt = out_img + 2048ll * 2048;
  gemm8_k<2><<<dim3(18, 16), 512, 0, stream>>>(h_i, h_t, 8192, w2_i, w2_t, 8192,
      img_mlp_b2, txt_mlp_b2, y1_i, y1_t, mod_i + 10240, mod_t + 10240, out_img, out_txt, 2048, 8192);
}

// Round 15
// 839.529 us; speedup vs baseline: 1.2516x; 1.0282x over previous
//
#include <hip/hip_runtime.h>

using u16 = unsigned short;
typedef __bf16 bf16x8 __attribute__((ext_vector_type(8)));
typedef float f32x4 __attribute__((ext_vector_type(4)));

__device__ inline u16 f2bf(float f){
  unsigned u = __float_as_uint(f);
  u += 0x7fff + ((u >> 16) & 1);   // RNE
  return (u16)(u >> 16);
}
__device__ inline float bf2f(u16 u){ return __uint_as_float((unsigned)u << 16); }

__device__ inline float wredsum(float v){
  #pragma unroll
  for (int o = 32; o; o >>= 1) v += __shfl_xor(v, o, 64);
  return v;
}

// direct global -> LDS DMA, 16B per lane; lds base must be wave-uniform
__device__ inline void gld16(const u16* g, u16* lds){
  __builtin_amdgcn_global_load_lds(
      (const __attribute__((address_space(1))) unsigned int*)g,
      (__attribute__((address_space(3))) unsigned int*)lds, 16, 0, 0);
}

// ---------------- mod matvec: out = silu(vec) @ W + b, W is 2048x12288 ----------------
__global__ void mod_matvec_k(const float* __restrict__ vec,
    const float* __restrict__ wi, const float* __restrict__ bi,
    const float* __restrict__ wt, const float* __restrict__ bt,
    float* __restrict__ oi, float* __restrict__ ot)
{
  __shared__ float sv[2048];
  __shared__ float red[4][64];
  int tid = threadIdx.x;
  for (int i = tid; i < 2048; i += 256){ float v = vec[i]; sv[i] = v / (1.0f + __expf(-v)); }
  __syncthreads();
  int j0 = blockIdx.x * 64;
  bool ist = j0 >= 12288;
  const float* w = ist ? wt : wi;
  const float* b = ist ? bt : bi;
  float* o = ist ? ot : oi;
  int col = (ist ? j0 - 12288 : j0) + (tid & 63);
  int kq = tid >> 6;
  float acc = 0.f;
  const float* wp = w + col;
  for (int k = kq * 512; k < kq * 512 + 512; ++k) acc += sv[k] * wp[(long long)k * 12288];
  red[kq][tid & 63] = acc;
  __syncthreads();
  if (kq == 0){
    o[col] = red[0][tid] + red[1][tid] + red[2][tid] + red[3][tid] + b[col];
  }
}

// ---------------- merged transpose + cast, 64x64 tiles: (K x N) f32 -> (N x K) bf16 ----------------
struct TcArgs {
  const float* in[8];
  u16* out[8];
  int K[8];
  int N[8];
  int base[9];   // prefix of 64x64-tile counts
};

__global__ void tcast64_k(TcArgs a)
{
  __shared__ float tile[64][65];
  int bid = blockIdx.x;
  int w = 0;
  #pragma unroll
  for (int i = 0; i < 8; ++i) if (bid >= a.base[i + 1]) w = i + 1;
  const float* in = a.in[w];
  u16* out = a.out[w];
  int K = a.K[w], N = a.N[w];
  int local = bid - a.base[w];
  int tx = N >> 6;
  int n0 = (local % tx) * 64, k0 = (local / tx) * 64;
  int tid = threadIdx.x;
  int r = tid >> 2, c0 = (tid & 3) * 16;
  const float* ir = &in[(long long)(k0 + r) * N + n0 + c0];
  #pragma unroll
  for (int j = 0; j < 4; ++j){
    float4 v = *(const float4*)&ir[j * 4];
    tile[r][c0 + j * 4 + 0] = v.x; tile[r][c0 + j * 4 + 1] = v.y;
    tile[r][c0 + j * 4 + 2] = v.z; tile[r][c0 + j * 4 + 3] = v.w;
  }
  __syncthreads();
  int n = tid >> 2, ks = (tid & 3) * 16;
  u16* orow = &out[(long long)(n0 + n) * K + k0 + ks];
  #pragma unroll
  for (int j = 0; j < 4; ++j){
    ushort4 o;
    o.x = f2bf(tile[ks + j * 4 + 0][n]);
    o.y = f2bf(tile[ks + j * 4 + 1][n]);
    o.z = f2bf(tile[ks + j * 4 + 2][n]);
    o.w = f2bf(tile[ks + j * 4 + 3][n]);
    *(ushort4*)&orow[j * 4] = o;
  }
}

// ---------------- LayerNorm + modulate (img+txt merged): out = (1+sc)*LN(x) + sh ----------------
__global__ void ln_mod_k(const float* __restrict__ xi, const float* __restrict__ xt,
    const float* __restrict__ sh_i, const float* __restrict__ sc_i,
    const float* __restrict__ sh_t, const float* __restrict__ sc_t,
    u16* __restrict__ oi, u16* __restrict__ ot)
{
  int row = blockIdx.x, tid = threadIdx.x;
  bool ist = row >= 2048;
  int r = ist ? row - 2048 : row;
  const float* xr = (ist ? xt : xi) + (long long)r * 2048;
  const float* sh = ist ? sh_t : sh_i;
  const float* sc = ist ? sc_t : sc_i;
  u16* orow = (ist ? ot : oi) + (long long)r * 2048;
  float v[8]; float s = 0.f, s2 = 0.f;
  #pragma unroll
  for (int j = 0; j < 8; ++j){ v[j] = xr[tid + j * 256]; s += v[j]; s2 += v[j] * v[j]; }
  s = wredsum(s); s2 = wredsum(s2);
  __shared__ float red[4][2];
  int wave = tid >> 6, lane = tid & 63;
  if (lane == 0){ red[wave][0] = s; red[wave][1] = s2; }
  __syncthreads();
  float S1 = red[0][0] + red[1][0] + red[2][0] + red[3][0];
  float S2 = red[0][1] + red[1][1] + red[2][1] + red[3][1];
  float mu = S1 * (1.0f / 2048.0f);
  float var = S2 * (1.0f / 2048.0f) - mu * mu;
  float rs = rsqrtf(var + 1e-6f);
  #pragma unroll
  for (int j = 0; j < 8; ++j){
    int c = tid + j * 256;
    orow[c] = f2bf((1.0f + sc[c]) * (v[j] - mu) * rs + sh[c]);
  }
}

// ------- QKV post (img+txt merged, bf16 in): RMSNorm(q,k) + RoPE + scatter -------
// Q/K [h][pos][d], Vt [h][d][pos]; img blocks bx<32 (pos0=256), txt bx>=32 (pos0=0).
__global__ void qkv_post_k(const u16* __restrict__ qkv_i, const u16* __restrict__ qkv_t,
    const float* __restrict__ qs_i, const float* __restrict__ ks_i,
    const float* __restrict__ qs_t, const float* __restrict__ ks_t,
    const float* __restrict__ pe,
    u16* __restrict__ Q, u16* __restrict__ Ko, u16* __restrict__ Vt)
{
  __shared__ u16 vs[128][72];
  int h = blockIdx.y;
  bool ist = blockIdx.x >= 32;
  int t0 = (ist ? blockIdx.x - 32 : blockIdx.x) * 64;
  const u16* qkv = ist ? qkv_t : qkv_i;
  const float* qs = ist ? qs_t : qs_i;
  const float* ks = ist ? ks_t : ks_i;
  int pos0 = ist ? 0 : 256;
  int tid = threadIdx.x, wave = tid >> 6, lane = tid & 63;
  for (int it = 0; it < 16; ++it){
    int tl = it * 4 + wave;
    int t = t0 + tl;
    const u16* rp = qkv + (long long)t * 6144 + h * 128;
    float q0 = bf2f(rp[lane]),        q1 = bf2f(rp[lane + 64]);
    float k0 = bf2f(rp[2048 + lane]), k1 = bf2f(rp[2048 + lane + 64]);
    float v0 = bf2f(rp[4096 + lane]), v1 = bf2f(rp[4096 + lane + 64]);
    float qss = wredsum(q0 * q0 + q1 * q1);
    float kss = wredsum(k0 * k0 + k1 * k1);
    float rq = rsqrtf(qss * (1.0f / 128.0f) + 1e-6f) * 0.08838834764831845f; // incl 1/sqrt(DH)
    float rk = rsqrtf(kss * (1.0f / 128.0f) + 1e-6f);
    float qn0 = q0 * rq * qs[lane], qn1 = q1 * rq * qs[lane + 64];
    float kn0 = k0 * rk * ks[lane], kn1 = k1 * rk * ks[lane + 64];
    int pos = pos0 + t;
    const float* peb = pe + (long long)pos * 256;
    bool odd = lane & 1;
    float4 p0 = *(const float4*)&peb[(lane >> 1) * 4];
    float4 p1 = *(const float4*)&peb[128 + (lane >> 1) * 4];
    float c00 = odd ? p0.z : p0.x, c01 = odd ? p0.w : p0.y;
    float c10 = odd ? p1.z : p1.x, c11 = odd ? p1.w : p1.y;
    float qp0 = __shfl_xor(qn0, 1, 64), qp1 = __shfl_xor(qn1, 1, 64);
    float kp0 = __shfl_xor(kn0, 1, 64), kp1 = __shfl_xor(kn1, 1, 64);
    float qe0 = odd ? qp0 : qn0, qo0 = odd ? qn0 : qp0;
    float qe1 = odd ? qp1 : qn1, qo1 = odd ? qn1 : qp1;
    float ke0 = odd ? kp0 : kn0, ko0 = odd ? kn0 : kp0;
    float ke1 = odd ? kp1 : kn1, ko1 = odd ? kn1 : kp1;
    u16* Qr = Q  + ((long long)h * 2304 + pos) * 128;
    u16* Kr = Ko + ((long long)h * 2304 + pos) * 128;
    Qr[lane]      = f2bf(c00 * qe0 + c01 * qo0);
    Qr[lane + 64] = f2bf(c10 * qe1 + c11 * qo1);
    Kr[lane]      = f2bf(c00 * ke0 + c01 * ko0);
    Kr[lane + 64] = f2bf(c10 * ke1 + c11 * ko1);
    vs[lane][tl]      = f2bf(v0);
    vs[lane + 64][tl] = f2bf(v1);
  }
  __syncthreads();
  int dd = tid >> 1, co = (tid & 1) * 32;
  u16* vr = Vt + ((long long)h * 128 + dd) * 2304 + pos0 + t0 + co;
  #pragma unroll
  for (int u = 0; u < 8; ++u)
    *(ushort4*)(vr + u * 4) = *(const ushort4*)&vs[dd][co + u * 4];
}

// ======== fused flash attention: grid (18 q-blocks, 16 heads), 8 waves ========
__global__ __launch_bounds__(512)
void fattn_k(const u16* __restrict__ Qb, const u16* __restrict__ Kb,
             const u16* __restrict__ Vt, u16* __restrict__ attn)
{
  __shared__ u16 Pl[128 * 128];      // Q staging first, then P
  __shared__ u16 Kl[128 * 128];
  __shared__ u16 Vl[2][128 * 128];

  const int tid  = threadIdx.x;
  const int lane = tid & 63;
  const int wave = tid >> 6;
  const int h  = blockIdx.y;
  const int q0 = blockIdx.x * 128;

  const u16* Qg = Qb + ((long long)h * 2304 + q0) * 128;
  const u16* Kg = Kb + (long long)h * 2304 * 128;
  const u16* Vg = Vt + (long long)h * 128 * 2304;

  const int s_r   = wave * 4 + (lane >> 4);
  const int s_oct = lane & 15;
  auto stage = [&](const u16* g, int ldg, u16* lds){
    #pragma unroll
    for (int i = 0; i < 4; ++i){
      int row = i * 32 + s_r;
      gld16(g + (long long)row * ldg + ((s_oct ^ (row & 7)) * 8),
            lds + (i * 32 + wave * 4) * 128);
    }
  };

  stage(Qg, 128, Pl);
  stage(Kg, 128, Kl);
  stage(Vg, 2304, Vl[0]);
  __syncthreads();

  const int frow = lane & 15;
  const int j0   = lane >> 4;
  const int qrow = wave * 16 + frow;
  bf16x8 aq[4];
  #pragma unroll
  for (int s = 0; s < 4; ++s)
    aq[s] = *(const bf16x8*)&Pl[qrow * 128 + (((s * 4 + j0) ^ (qrow & 7)) * 8)];
  __syncthreads();

  float mrun[4], lrun[4];
  #pragma unroll
  for (int j = 0; j < 4; ++j){ mrun[j] = -3.0e38f; lrun[j] = 0.f; }
  f32x4 oacc[8] = {};

  for (int t = 0; t < 18; ++t){
    asm volatile("s_waitcnt vmcnt(0)" ::: "memory");
    __builtin_amdgcn_sched_barrier(0);
    __builtin_amdgcn_s_barrier();
    __builtin_amdgcn_sched_barrier(0);

    f32x4 sacc[8] = {};
    #pragma unroll
    for (int s = 0; s < 4; ++s){
      #pragma unroll
      for (int n = 0; n < 8; ++n){
        int kr = n * 16 + frow;
        bf16x8 bk = *(const bf16x8*)&Kl[kr * 128 + (((s * 4 + j0) ^ (kr & 7)) * 8)];
        sacc[n] = __builtin_amdgcn_mfma_f32_16x16x32_bf16(aq[s], bk, sacc[n], 0, 0, 0);
      }
    }
    __builtin_amdgcn_sched_barrier(0);
    __builtin_amdgcn_s_barrier();
    __builtin_amdgcn_sched_barrier(0);
    if (t + 1 < 18){
      stage(Kg + (long long)(t + 1) * 128 * 128, 128, Kl);
      stage(Vg + (t + 1) * 128, 2304, Vl[(t + 1) & 1]);
    }
    __builtin_amdgcn_sched_barrier(0);

    float mnew[4], scl[4];
    #pragma unroll
    for (int j = 0; j < 4; ++j){
      float v = sacc[0][j];
      #pragma unroll
      for (int n = 1; n < 8; ++n) v = fmaxf(v, sacc[n][j]);
      #pragma unroll
      for (int o = 8; o; o >>= 1) v = fmaxf(v, __shfl_xor(v, o, 64));
      mnew[j] = fmaxf(mrun[j], v);
      scl[j] = __expf(mrun[j] - mnew[j]);
      mrun[j] = mnew[j];
    }
    #pragma unroll
    for (int j = 0; j < 4; ++j){
      const int row = wave * 16 + j0 * 4 + j;
      float rsum = 0.f;
      #pragma unroll
      for (int n = 0; n < 8; ++n){
        float p = __expf(sacc[n][j] - mnew[j]);
        rsum += p;
        int col = n * 16 + frow;
        Pl[row * 128 + (((col >> 3) ^ (row & 7)) << 3) + (col & 7)] = f2bf(p);
      }
      #pragma unroll
      for (int o = 8; o; o >>= 1) rsum += __shfl_xor(rsum, o, 64);
      lrun[j] = lrun[j] * scl[j] + rsum;
      #pragma unroll
      for (int n = 0; n < 8; ++n) oacc[n][j] *= scl[j];
    }
    asm volatile("s_waitcnt lgkmcnt(0)" ::: "memory");
    __builtin_amdgcn_sched_barrier(0);

    const u16* vl = Vl[t & 1];
    #pragma unroll
    for (int s = 0; s < 4; ++s){
      bf16x8 ap = *(const bf16x8*)&Pl[qrow * 128 + (((s * 4 + j0) ^ (qrow & 7)) * 8)];
      #pragma unroll
      for (int n = 0; n < 8; ++n){
        int dr = n * 16 + frow;
        bf16x8 bv = *(const bf16x8*)&vl[dr * 128 + (((s * 4 + j0) ^ (dr & 7)) * 8)];
        oacc[n] = __builtin_amdgcn_mfma_f32_16x16x32_bf16(ap, bv, oacc[n], 0, 0, 0);
      }
    }
    __builtin_amdgcn_sched_barrier(0);
  }

  float inv[4];
  #pragma unroll
  for (int j = 0; j < 4; ++j) inv[j] = 1.0f / lrun[j];
  #pragma unroll
  for (int n = 0; n < 8; ++n){
    int d = n * 16 + frow;
    #pragma unroll
    for (int j = 0; j < 4; ++j){
      int row = wave * 16 + j0 * 4 + j;
      attn[(long long)(q0 + row) * 2048 + h * 128 + d] = f2bf(oacc[n][j] * inv[j]);
    }
  }
}

// ======== 8-wave depth-2 GEMM, 128x128 tile, BK=64, img+txt merged, XCD panel-chunks ========
// MODE 0: f32 = acc+bias ; 1: bf16 = acc+bias ; 2: f32 = res + gate[col]*(acc+bias) ;
// 3: bf16 = gelu(acc+bias)
template<int MODE>
__global__ __launch_bounds__(512)
void gemm8_k(const u16* __restrict__ Ai, const u16* __restrict__ At, int lda,
             const u16* __restrict__ Bi, const u16* __restrict__ Bt, int ldb,
             const float* __restrict__ bias_i, const float* __restrict__ bias_t,
             const float* __restrict__ res_i,  const float* __restrict__ res_t,
             const float* __restrict__ gate_i, const float* __restrict__ gate_t,
             void* __restrict__ Ci, void* __restrict__ Ct, int ldc, int K)
{
  constexpr int BK = 64;
  constexpr int MR = 4, NR = 2;        // wave tile 64x32 (8 waves as 2M x 4N)
  constexpr int AI = 2, BI = 2;

  __shared__ u16 As[2][128 * BK];
  __shared__ u16 Bs[2][128 * BK];

  const int tid  = threadIdx.x;
  const int lane = tid & 63;
  const int wave = tid >> 6;
  const int wm = wave >> 2;
  const int wn = wave & 3;

  const int gx = gridDim.x;
  const int nwg = gx * gridDim.y;
  const int n = blockIdx.x + gx * blockIdx.y;
  const int s_id = (n & 7) * (nwg >> 3) + (n >> 3);
  const int bx = s_id % gx;
  const int by = s_id / gx;

  const bool ist = bx >= 16;
  const int rb = ist ? bx - 16 : bx;
  const u16* Ab = (ist ? At : Ai) + (long long)rb * 128 * lda;
  const u16* Bb = (ist ? Bt : Bi) + (long long)by * 128 * ldb;
  const float* bias = ist ? bias_t : bias_i;
  const float* res  = ist ? res_t  : res_i;
  const float* gate = ist ? gate_t : gate_i;
  void* C = ist ? Ct : Ci;

  const int srow = wave * 8 + (lane >> 3);
  const int sgo  = ((lane & 7) ^ ((lane >> 3) & 7)) * 8;   // u16 units
  const u16* agp[AI]; const u16* bgp[BI];
  int alo[AI], blo[BI];
  #pragma unroll
  for (int i = 0; i < AI; ++i){
    agp[i] = Ab + (long long)(i * 64 + srow) * lda + sgo;
    alo[i] = (i * 64 + wave * 8) * BK;
  }
  #pragma unroll
  for (int i = 0; i < BI; ++i){
    bgp[i] = Bb + (long long)(i * 64 + srow) * ldb + sgo;
    blo[i] = (i * 64 + wave * 8) * BK;
  }

  const int arow0 = wm * 64;
  const int frow  = lane & 15;
  const int fx    = lane & 7;
  const int j0    = lane >> 4;

  f32x4 acc[MR][NR] = {};

  #pragma unroll
  for (int i = 0; i < AI; ++i) gld16(agp[i], &As[0][alo[i]]);
  #pragma unroll
  for (int i = 0; i < BI; ++i) gld16(bgp[i], &Bs[0][blo[i]]);
  __builtin_amdgcn_sched_barrier(0);

  const int nt = K / BK;
  for (int t = 0; t < nt; ++t){
    if (t + 1 < nt){
      int k0 = (t + 1) * BK;
      int nb = (t + 1) & 1;
      #pragma unroll
      for (int i = 0; i < AI; ++i) gld16(agp[i] + k0, &As[nb][alo[i]]);
      #pragma unroll
      for (int i = 0; i < BI; ++i) gld16(bgp[i] + k0, &Bs[nb][blo[i]]);
      __builtin_amdgcn_sched_barrier(0);
      asm volatile("s_waitcnt vmcnt(4)" ::: "memory");
    } else {
      asm volatile("s_waitcnt vmcnt(0)" ::: "memory");
    }
    __builtin_amdgcn_sched_barrier(0);
    __builtin_amdgcn_s_barrier();
    __builtin_amdgcn_sched_barrier(0);

    const u16* as = As[t & 1];
    const u16* bs = Bs[t & 1];
    #pragma unroll
    for (int s = 0; s < 2; ++s){
      const int oct = (s * 4 + j0) ^ fx;
      bf16x8 bfr[NR];
      #pragma unroll
      for (int nn = 0; nn < NR; ++nn)
        bfr[nn] = *(const bf16x8*)&bs[(wn * 32 + nn * 16 + frow) * BK + oct * 8];
      __builtin_amdgcn_s_setprio(1);
      #pragma unroll
      for (int m = 0; m < MR; ++m){
        bf16x8 af = *(const bf16x8*)&as[(arow0 + m * 16 + frow) * BK + oct * 8];
        #pragma unroll
        for (int nn = 0; nn < NR; ++nn)
          acc[m][nn] = __builtin_amdgcn_mfma_f32_16x16x32_bf16(af, bfr[nn], acc[m][nn], 0, 0, 0);
      }
      __builtin_amdgcn_s_setprio(0);
    }
    __builtin_amdgcn_sched_barrier(0);
    __builtin_amdgcn_s_barrier();
    __builtin_amdgcn_sched_barrier(0);
  }

  const int lr = (lane >> 4) * 4;
  const int lc = lane & 15;
  const long long rowb = (long long)rb * 128 + arow0;
  const long long colb = (long long)by * 128 + wn * 32;
  #pragma unroll
  for (int mi = 0; mi < MR; ++mi){
    #pragma unroll
    for (int ni = 0; ni < NR; ++ni){
      long long col = colb + ni * 16 + lc;
      float bv = bias ? bias[col] : 0.0f;
      #pragma unroll
      for (int j = 0; j < 4; ++j){
        long long row = rowb + mi * 16 + lr + j;
        float v = acc[mi][ni][j] + bv;
        long long ci = row * (long long)ldc + col;
        if constexpr (MODE == 0) ((float*)C)[ci] = v;
        else if constexpr (MODE == 1) ((u16*)C)[ci] = f2bf(v);
        else if constexpr (MODE == 2) ((float*)C)[ci] = res[ci] + gate[col] * v;
        else {
          float z2 = 1.5957691216057308f * (v + 0.044715f * v * v * v);
          ((u16*)C)[ci] = f2bf(v / (1.0f + __expf(-z2)));
        }
      }
    }
  }
}

extern "C" void kernel_launch(void* const* d_in, const int* in_sizes, int n_in,
                              void* d_out, int out_size, void* d_ws, size_t ws_size,
                              hipStream_t stream)
{
  const float* img        = (const float*)d_in[0];
  const float* txt        = (const float*)d_in[1];
  const float* vec        = (const float*)d_in[2];
  const float* img_mod_w  = (const float*)d_in[3];
  const float* img_mod_b  = (const float*)d_in[4];
  const float* txt_mod_w  = (const float*)d_in[5];
  const float* txt_mod_b  = (const float*)d_in[6];
  const float* img_qkv_w  = (const float*)d_in[7];
  const float* img_qkv_b  = (const float*)d_in[8];
  const float* img_q_s    = (const float*)d_in[9];
  const float* img_k_s    = (const float*)d_in[10];
  const float* txt_qkv_w  = (const float*)d_in[11];
  const float* txt_qkv_b  = (const float*)d_in[12];
  const float* txt_q_s    = (const float*)d_in[13];
  const float* txt_k_s    = (const float*)d_in[14];
  const float* img_proj_w = (const float*)d_in[15];
  const float* img_proj_b = (const float*)d_in[16];
  const float* txt_proj_w = (const float*)d_in[17];
  const float* txt_proj_b = (const float*)d_in[18];
  const float* img_mlp_w1 = (const float*)d_in[19];
  const float* img_mlp_b1 = (const float*)d_in[20];
  const float* img_mlp_w2 = (const float*)d_in[21];
  const float* img_mlp_b2 = (const float*)d_in[22];
  const float* txt_mlp_w1 = (const float*)d_in[23];
  const float* txt_mlp_b1 = (const float*)d_in[24];
  const float* txt_mlp_w2 = (const float*)d_in[25];
  const float* txt_mlp_b2 = (const float*)d_in[26];
  const float* pe         = (const float*)d_in[27];

  char* ws = (char*)d_ws;
  size_t off = 0;
  auto alloc = [&](size_t b){ void* p = ws + off; off = (off + b + 255) & ~(size_t)255; return p; };

  u16* wq_i = (u16*)alloc(6144ll * 2048 * 2);
  u16* wq_t = (u16*)alloc(6144ll * 2048 * 2);
  u16* wp_i = (u16*)alloc(2048ll * 2048 * 2);
  u16* wp_t = (u16*)alloc(2048ll * 2048 * 2);
  u16* w1_i = (u16*)alloc(8192ll * 2048 * 2);
  u16* w1_t = (u16*)alloc(8192ll * 2048 * 2);
  u16* w2_i = (u16*)alloc(2048ll * 8192 * 2);
  u16* w2_t = (u16*)alloc(2048ll * 8192 * 2);
  float* mod_i = (float*)alloc(12288 * 4);
  float* mod_t = (float*)alloc(12288 * 4);
  u16* Qb   = (u16*)alloc(16ll * 2304 * 128 * 2);
  u16* Kb   = (u16*)alloc(16ll * 2304 * 128 * 2);
  u16* Vt   = (u16*)alloc(16ll * 2304 * 128 * 2);
  u16* attn = (u16*)alloc(2304ll * 2048 * 2);
  char* big = (char*)alloc(4ll * 2304 * 2304 * 4);   // 84.9 MB reused region

  // phase 1 views (qkv now bf16)
  u16*   xin_i = (u16*)big;
  u16*   xin_t = (u16*)(big + 8388608);
  u16*   qkv_i = (u16*)(big + 9437184);                 // 25.2 MB
  u16*   qkv_t = (u16*)(big + 9437184 + 25165824);      // 3.1 MB
  // phase 3 views
  float* y1_i  = (float*)big;
  float* y1_t  = (float*)(big + 16777216);
  u16*   ln2_i = (u16*)(big + 18874368);
  u16*   ln2_t = (u16*)(big + 27262976);
  u16*   h_i   = (u16*)(big + 28311552);
  u16*   h_t   = (u16*)(big + 61865984);

  // modulation vectors
  mod_matvec_k<<<384, 256, 0, stream>>>(vec, img_mod_w, img_mod_b, txt_mod_w, txt_mod_b, mod_i, mod_t);

  // merged weight cast + transpose to (N x K) bf16, 64x64 tiles
  {
    TcArgs a;
    const float* ins[8] = {img_qkv_w, txt_qkv_w, img_proj_w, txt_proj_w,
                           img_mlp_w1, txt_mlp_w1, img_mlp_w2, txt_mlp_w2};
    u16* outs[8] = {wq_i, wq_t, wp_i, wp_t, w1_i, w1_t, w2_i, w2_t};
    int Ks[8] = {2048, 2048, 2048, 2048, 2048, 2048, 8192, 8192};
    int Ns[8] = {6144, 6144, 2048, 2048, 8192, 8192, 2048, 2048};
    int b = 0;
    for (int i = 0; i < 8; ++i){
      a.in[i] = ins[i]; a.out[i] = outs[i]; a.K[i] = Ks[i]; a.N[i] = Ns[i];
      a.base[i] = b;
      b += (Ks[i] >> 6) * (Ns[i] >> 6);
    }
    a.base[8] = b;
    tcast64_k<<<b, 256, 0, stream>>>(a);
  }

  // LN1 + modulate (img+txt merged)
  ln_mod_k<<<2304, 256, 0, stream>>>(img, txt, mod_i, mod_i + 2048, mod_t, mod_t + 2048, xin_i, xin_t);

  // QKV GEMM (bf16 out; img+txt merged: 18x48 = 864 blocks)
  gemm8_k<1><<<dim3(18, 48), 512, 0, stream>>>(xin_i, xin_t, 2048, wq_i, wq_t, 2048,
      img_qkv_b, txt_qkv_b, nullptr, nullptr, nullptr, nullptr, qkv_i, qkv_t, 6144, 2048);

  // RMSNorm + RoPE + scatter (merged: grid 36x16)
  qkv_post_k<<<dim3(36, 16), 256, 0, stream>>>(qkv_i, qkv_t, img_q_s, img_k_s, txt_q_s, txt_k_s,
      pe, Qb, Kb, Vt);

  // fused flash attention
  fattn_k<<<dim3(18, 16), 512, 0, stream>>>(Qb, Kb, Vt, attn);

  // projections with residual + gate (merged: 18x16 = 288 blocks)
  gemm8_k<2><<<dim3(18, 16), 512, 0, stream>>>(attn + 256 * 2048, attn, 2048, wp_i, wp_t, 2048,
      img_proj_b, txt_proj_b, img, txt, mod_i + 4096, mod_t + 4096, y1_i, y1_t, 2048, 2048);

  // LN2 + modulate (merged)
  ln_mod_k<<<2304, 256, 0, stream>>>(y1_i, y1_t, mod_i + 6144, mod_i + 8192, mod_t + 6144, mod_t + 8192, ln2_i, ln2_t);

  // MLP1 (GELU fused; merged: 18x64 = 1152 blocks)
  gemm8_k<3><<<dim3(18, 64), 512, 0, stream>>>(ln2_i, ln2_t, 2048, w1_i, w1_t, 2048,
      img_mlp_b1, txt_mlp_b1, nullptr, nullptr, nullptr, nullptr, h_i, h_t, 8192, 2048);

  // MLP2 with residual + gate -> final outputs (merged: 18x16 = 288 blocks)
  float* out_img = (float*)d_out;
  float* out_txt = out_img + 2048ll * 2048;
  gemm8_k<2><<<dim3(18, 16), 512, 0, stream>>>(h_i, h_t, 8192, w2_i, w2_t, 8192,
      img_mlp_b2, txt_mlp_b2, y1_i, y1_t, mod_i + 10240, mod_t + 10240, out_img, out_txt, 2048, 8192);
}

// Round 16
// 827.115 us; speedup vs baseline: 1.2703x; 1.0150x over previous
//
#include <hip/hip_runtime.h>

using u16 = unsigned short;
typedef __bf16 bf16x8 __attribute__((ext_vector_type(8)));
typedef float f32x4 __attribute__((ext_vector_type(4)));

__device__ inline u16 f2bf(float f){
  unsigned u = __float_as_uint(f);
  u += 0x7fff + ((u >> 16) & 1);   // RNE
  return (u16)(u >> 16);
}
__device__ inline float bf2f(u16 u){ return __uint_as_float((unsigned)u << 16); }

__device__ inline float wredsum(float v){
  #pragma unroll
  for (int o = 32; o; o >>= 1) v += __shfl_xor(v, o, 64);
  return v;
}

// direct global -> LDS DMA, 16B per lane; lds base must be wave-uniform
__device__ inline void gld16(const u16* g, u16* lds){
  __builtin_amdgcn_global_load_lds(
      (const __attribute__((address_space(1))) unsigned int*)g,
      (__attribute__((address_space(3))) unsigned int*)lds, 16, 0, 0);
}

// ---------------- mod matvec: out = silu(vec) @ W + b, W is 2048x12288 ----------------
__global__ void mod_matvec_k(const float* __restrict__ vec,
    const float* __restrict__ wi, const float* __restrict__ bi,
    const float* __restrict__ wt, const float* __restrict__ bt,
    float* __restrict__ oi, float* __restrict__ ot)
{
  __shared__ float sv[2048];
  __shared__ float red[4][64];
  int tid = threadIdx.x;
  for (int i = tid; i < 2048; i += 256){ float v = vec[i]; sv[i] = v / (1.0f + __expf(-v)); }
  __syncthreads();
  int j0 = blockIdx.x * 64;
  bool ist = j0 >= 12288;
  const float* w = ist ? wt : wi;
  const float* b = ist ? bt : bi;
  float* o = ist ? ot : oi;
  int col = (ist ? j0 - 12288 : j0) + (tid & 63);
  int kq = tid >> 6;
  float acc = 0.f;
  const float* wp = w + col;
  for (int k = kq * 512; k < kq * 512 + 512; ++k) acc += sv[k] * wp[(long long)k * 12288];
  red[kq][tid & 63] = acc;
  __syncthreads();
  if (kq == 0){
    o[col] = red[0][tid] + red[1][tid] + red[2][tid] + red[3][tid] + b[col];
  }
}

// ---------------- merged transpose + cast, 64x64 tiles: (K x N) f32 -> (N x K) bf16 ----------------
struct TcArgs {
  const float* in[8];
  u16* out[8];
  int K[8];
  int N[8];
  int base[9];   // prefix of 64x64-tile counts
};

__global__ void tcast64_k(TcArgs a)
{
  __shared__ float tile[64][65];
  int bid = blockIdx.x;
  int w = 0;
  #pragma unroll
  for (int i = 0; i < 8; ++i) if (bid >= a.base[i + 1]) w = i + 1;
  const float* in = a.in[w];
  u16* out = a.out[w];
  int K = a.K[w], N = a.N[w];
  int local = bid - a.base[w];
  int tx = N >> 6;
  int n0 = (local % tx) * 64, k0 = (local / tx) * 64;
  int tid = threadIdx.x;
  int r = tid >> 2, c0 = (tid & 3) * 16;
  const float* ir = &in[(long long)(k0 + r) * N + n0 + c0];
  #pragma unroll
  for (int j = 0; j < 4; ++j){
    float4 v = *(const float4*)&ir[j * 4];
    tile[r][c0 + j * 4 + 0] = v.x; tile[r][c0 + j * 4 + 1] = v.y;
    tile[r][c0 + j * 4 + 2] = v.z; tile[r][c0 + j * 4 + 3] = v.w;
  }
  __syncthreads();
  int n = tid >> 2, ks = (tid & 3) * 16;
  u16* orow = &out[(long long)(n0 + n) * K + k0 + ks];
  #pragma unroll
  for (int j = 0; j < 4; ++j){
    ushort4 o;
    o.x = f2bf(tile[ks + j * 4 + 0][n]);
    o.y = f2bf(tile[ks + j * 4 + 1][n]);
    o.z = f2bf(tile[ks + j * 4 + 2][n]);
    o.w = f2bf(tile[ks + j * 4 + 3][n]);
    *(ushort4*)&orow[j * 4] = o;
  }
}

// ---------------- LayerNorm + modulate (img+txt merged): out = (1+sc)*LN(x) + sh ----------------
__global__ void ln_mod_k(const float* __restrict__ xi, const float* __restrict__ xt,
    const float* __restrict__ sh_i, const float* __restrict__ sc_i,
    const float* __restrict__ sh_t, const float* __restrict__ sc_t,
    u16* __restrict__ oi, u16* __restrict__ ot)
{
  int row = blockIdx.x, tid = threadIdx.x;
  bool ist = row >= 2048;
  int r = ist ? row - 2048 : row;
  const float* xr = (ist ? xt : xi) + (long long)r * 2048;
  const float* sh = ist ? sh_t : sh_i;
  const float* sc = ist ? sc_t : sc_i;
  u16* orow = (ist ? ot : oi) + (long long)r * 2048;
  float v[8]; float s = 0.f, s2 = 0.f;
  #pragma unroll
  for (int j = 0; j < 8; ++j){ v[j] = xr[tid + j * 256]; s += v[j]; s2 += v[j] * v[j]; }
  s = wredsum(s); s2 = wredsum(s2);
  __shared__ float red[4][2];
  int wave = tid >> 6, lane = tid & 63;
  if (lane == 0){ red[wave][0] = s; red[wave][1] = s2; }
  __syncthreads();
  float S1 = red[0][0] + red[1][0] + red[2][0] + red[3][0];
  float S2 = red[0][1] + red[1][1] + red[2][1] + red[3][1];
  float mu = S1 * (1.0f / 2048.0f);
  float var = S2 * (1.0f / 2048.0f) - mu * mu;
  float rs = rsqrtf(var + 1e-6f);
  #pragma unroll
  for (int j = 0; j < 8; ++j){
    int c = tid + j * 256;
    orow[c] = f2bf((1.0f + sc[c]) * (v[j] - mu) * rs + sh[c]);
  }
}

// ------- QKV post (img+txt merged, bf16 in): RMSNorm(q,k) + RoPE + scatter -------
__global__ void qkv_post_k(const u16* __restrict__ qkv_i, const u16* __restrict__ qkv_t,
    const float* __restrict__ qs_i, const float* __restrict__ ks_i,
    const float* __restrict__ qs_t, const float* __restrict__ ks_t,
    const float* __restrict__ pe,
    u16* __restrict__ Q, u16* __restrict__ Ko, u16* __restrict__ Vt)
{
  __shared__ u16 vs[128][72];
  int h = blockIdx.y;
  bool ist = blockIdx.x >= 32;
  int t0 = (ist ? blockIdx.x - 32 : blockIdx.x) * 64;
  const u16* qkv = ist ? qkv_t : qkv_i;
  const float* qs = ist ? qs_t : qs_i;
  const float* ks = ist ? ks_t : ks_i;
  int pos0 = ist ? 0 : 256;
  int tid = threadIdx.x, wave = tid >> 6, lane = tid & 63;
  for (int it = 0; it < 16; ++it){
    int tl = it * 4 + wave;
    int t = t0 + tl;
    const u16* rp = qkv + (long long)t * 6144 + h * 128;
    float q0 = bf2f(rp[lane]),        q1 = bf2f(rp[lane + 64]);
    float k0 = bf2f(rp[2048 + lane]), k1 = bf2f(rp[2048 + lane + 64]);
    float v0 = bf2f(rp[4096 + lane]), v1 = bf2f(rp[4096 + lane + 64]);
    float qss = wredsum(q0 * q0 + q1 * q1);
    float kss = wredsum(k0 * k0 + k1 * k1);
    float rq = rsqrtf(qss * (1.0f / 128.0f) + 1e-6f) * 0.08838834764831845f; // incl 1/sqrt(DH)
    float rk = rsqrtf(kss * (1.0f / 128.0f) + 1e-6f);
    float qn0 = q0 * rq * qs[lane], qn1 = q1 * rq * qs[lane + 64];
    float kn0 = k0 * rk * ks[lane], kn1 = k1 * rk * ks[lane + 64];
    int pos = pos0 + t;
    const float* peb = pe + (long long)pos * 256;
    bool odd = lane & 1;
    float4 p0 = *(const float4*)&peb[(lane >> 1) * 4];
    float4 p1 = *(const float4*)&peb[128 + (lane >> 1) * 4];
    float c00 = odd ? p0.z : p0.x, c01 = odd ? p0.w : p0.y;
    float c10 = odd ? p1.z : p1.x, c11 = odd ? p1.w : p1.y;
    float qp0 = __shfl_xor(qn0, 1, 64), qp1 = __shfl_xor(qn1, 1, 64);
    float kp0 = __shfl_xor(kn0, 1, 64), kp1 = __shfl_xor(kn1, 1, 64);
    float qe0 = odd ? qp0 : qn0, qo0 = odd ? qn0 : qp0;
    float qe1 = odd ? qp1 : qn1, qo1 = odd ? qn1 : qp1;
    float ke0 = odd ? kp0 : kn0, ko0 = odd ? kn0 : kp0;
    float ke1 = odd ? kp1 : kn1, ko1 = odd ? kn1 : kp1;
    u16* Qr = Q  + ((long long)h * 2304 + pos) * 128;
    u16* Kr = Ko + ((long long)h * 2304 + pos) * 128;
    Qr[lane]      = f2bf(c00 * qe0 + c01 * qo0);
    Qr[lane + 64] = f2bf(c10 * qe1 + c11 * qo1);
    Kr[lane]      = f2bf(c00 * ke0 + c01 * ko0);
    Kr[lane + 64] = f2bf(c10 * ke1 + c11 * ko1);
    vs[lane][tl]      = f2bf(v0);
    vs[lane + 64][tl] = f2bf(v1);
  }
  __syncthreads();
  int dd = tid >> 1, co = (tid & 1) * 32;
  u16* vr = Vt + ((long long)h * 128 + dd) * 2304 + pos0 + t0 + co;
  #pragma unroll
  for (int u = 0; u < 8; ++u)
    *(ushort4*)(vr + u * 4) = *(const ushort4*)&vs[dd][co + u * 4];
}

// ======== fused flash attention, KV=64 tiles, 80KB LDS (2 WG/CU), 1 barrier/tile ========
// Q frags in regs; K,V both double-buffered (stage(t+1) issues right after top barrier,
// WAR safe: writes go to buf^1 whose readers finished before this barrier). P intra-wave.
__global__ __launch_bounds__(512)
void fattn_k(const u16* __restrict__ Qb, const u16* __restrict__ Kb,
             const u16* __restrict__ Vt, u16* __restrict__ attn)
{
  __shared__ u16 Kl[2][64 * 128];    // Q staged flat here first (32 KB)
  __shared__ u16 Vl[2][128 * 64];
  __shared__ u16 Pl[128 * 64];

  const int tid  = threadIdx.x;
  const int lane = tid & 63;
  const int wave = tid >> 6;
  const int h  = blockIdx.y;
  const int q0 = blockIdx.x * 128;

  const u16* Qg = Qb + ((long long)h * 2304 + q0) * 128;
  const u16* Kg = Kb + (long long)h * 2304 * 128;
  const u16* Vg = Vt + (long long)h * 128 * 2304;

  u16* Qlds = &Kl[0][0];             // 128x128 flat

  // 16-octet row staging helpers (128-col tiles): wave covers 4 rows per instr
  const int r16 = wave * 4 + (lane >> 4);
  const int o16 = lane & 15;
  // 8-octet row staging (64-col tiles): wave covers 8 rows per instr
  const int r8 = wave * 8 + (lane >> 3);
  const int o8 = lane & 7;

  // stage Q (128 rows x 128): src octet ^ (row&7) so lds[r][o]=g[r][o^(r&7)]
  #pragma unroll
  for (int i = 0; i < 4; ++i){
    int row = i * 32 + r16;
    gld16(Qg + (long long)row * 128 + ((o16 ^ (row & 7)) * 8),
          Qlds + (i * 32 + wave * 4) * 128);
  }
  __syncthreads();

  const int frow = lane & 15;
  const int j0   = lane >> 4;
  const int qrow = wave * 16 + frow;
  bf16x8 aq[4];
  #pragma unroll
  for (int s = 0; s < 4; ++s)
    aq[s] = *(const bf16x8*)&Qlds[qrow * 128 + (((s * 4 + j0) ^ (qrow & 7)) * 8)];
  __syncthreads();                   // all Q reads done; Kl free

  auto stageK = [&](int t, int b){
    #pragma unroll
    for (int i = 0; i < 2; ++i){
      int row = i * 32 + r16;        // local kv row (64 mult of 8 -> &7 same as global)
      gld16(Kg + (long long)(t * 64 + row) * 128 + ((o16 ^ (row & 7)) * 8),
            &Kl[b][(i * 32 + wave * 4) * 128]);
    }
  };
  auto stageV = [&](int t, int b){
    #pragma unroll
    for (int i = 0; i < 2; ++i){
      int row = i * 64 + r8;         // d row 0..127
      gld16(Vg + (long long)row * 2304 + t * 64 + ((o8 ^ (row & 7)) * 8),
            &Vl[b][(i * 64 + wave * 8) * 64]);
    }
  };

  stageK(0, 0); stageV(0, 0);
  __builtin_amdgcn_sched_barrier(0);

  float mrun[4], lrun[4];
  #pragma unroll
  for (int j = 0; j < 4; ++j){ mrun[j] = -3.0e38f; lrun[j] = 0.f; }
  f32x4 oacc[8] = {};

  for (int t = 0; t < 36; ++t){
    const int cur = t & 1;
    asm volatile("s_waitcnt vmcnt(0)" ::: "memory");   // K(t),V(t) resident
    __builtin_amdgcn_sched_barrier(0);
    __builtin_amdgcn_s_barrier();                      // also fences buf^1 WAR
    __builtin_amdgcn_sched_barrier(0);
    if (t + 1 < 36){ stageK(t + 1, cur ^ 1); stageV(t + 1, cur ^ 1); }
    __builtin_amdgcn_sched_barrier(0);

    // QK^T: 16 MFMA (4 k-steps x 4 kv-frags)
    f32x4 sacc[4] = {};
    #pragma unroll
    for (int s = 0; s < 4; ++s){
      #pragma unroll
      for (int n = 0; n < 4; ++n){
        int kr = n * 16 + frow;
        bf16x8 bk = *(const bf16x8*)&Kl[cur][kr * 128 + (((s * 4 + j0) ^ (kr & 7)) * 8)];
        sacc[n] = __builtin_amdgcn_mfma_f32_16x16x32_bf16(aq[s], bk, sacc[n], 0, 0, 0);
      }
    }

    // online softmax (rows = wave*16 + j0*4 + j; 16-lane groups share a row)
    float mnew[4], scl[4];
    #pragma unroll
    for (int j = 0; j < 4; ++j){
      float v = fmaxf(fmaxf(sacc[0][j], sacc[1][j]), fmaxf(sacc[2][j], sacc[3][j]));
      #pragma unroll
      for (int o = 8; o; o >>= 1) v = fmaxf(v, __shfl_xor(v, o, 64));
      mnew[j] = fmaxf(mrun[j], v);
      scl[j] = __expf(mrun[j] - mnew[j]);
      mrun[j] = mnew[j];
    }
    #pragma unroll
    for (int j = 0; j < 4; ++j){
      const int row = wave * 16 + j0 * 4 + j;
      float rsum = 0.f;
      #pragma unroll
      for (int n = 0; n < 4; ++n){
        float p = __expf(sacc[n][j] - mnew[j]);
        rsum += p;
        int col = n * 16 + frow;
        Pl[row * 64 + (((col >> 3) ^ (row & 7)) << 3) + (col & 7)] = f2bf(p);
      }
      #pragma unroll
      for (int o = 8; o; o >>= 1) rsum += __shfl_xor(rsum, o, 64);
      lrun[j] = lrun[j] * scl[j] + rsum;
      #pragma unroll
      for (int n = 0; n < 8; ++n) oacc[n][j] *= scl[j];
    }
    asm volatile("s_waitcnt lgkmcnt(0)" ::: "memory"); // own-stripe P writes retired
    __builtin_amdgcn_sched_barrier(0);

    // PV: 16 MFMA (2 k-steps x 8 d-frags)
    #pragma unroll
    for (int s = 0; s < 2; ++s){
      bf16x8 ap = *(const bf16x8*)&Pl[qrow * 64 + (((s * 4 + j0) ^ (qrow & 7)) * 8)];
      #pragma unroll
      for (int n = 0; n < 8; ++n){
        int dr = n * 16 + frow;
        bf16x8 bv = *(const bf16x8*)&Vl[cur][dr * 64 + (((s * 4 + j0) ^ (dr & 7)) * 8)];
        oacc[n] = __builtin_amdgcn_mfma_f32_16x16x32_bf16(ap, bv, oacc[n], 0, 0, 0);
      }
    }
    __builtin_amdgcn_sched_barrier(0);
  }

  float inv[4];
  #pragma unroll
  for (int j = 0; j < 4; ++j) inv[j] = 1.0f / lrun[j];
  #pragma unroll
  for (int n = 0; n < 8; ++n){
    int d = n * 16 + frow;
    #pragma unroll
    for (int j = 0; j < 4; ++j){
      int row = wave * 16 + j0 * 4 + j;
      attn[(long long)(q0 + row) * 2048 + h * 128 + d] = f2bf(oacc[n][j] * inv[j]);
    }
  }
}

// ======== 8-wave depth-2 GEMM, 128x128 tile, BK=64, img+txt merged, XCD panel-chunks ========
// MODE 0: f32 = acc+bias ; 1: bf16 = acc+bias ; 2: f32 = res + gate[col]*(acc+bias) ;
// 3: bf16 = gelu(acc+bias)
template<int MODE>
__global__ __launch_bounds__(512)
void gemm8_k(const u16* __restrict__ Ai, const u16* __restrict__ At, int lda,
             const u16* __restrict__ Bi, const u16* __restrict__ Bt, int ldb,
             const float* __restrict__ bias_i, const float* __restrict__ bias_t,
             const float* __restrict__ res_i,  const float* __restrict__ res_t,
             const float* __restrict__ gate_i, const float* __restrict__ gate_t,
             void* __restrict__ Ci, void* __restrict__ Ct, int ldc, int K)
{
  constexpr int BK = 64;
  constexpr int MR = 4, NR = 2;        // wave tile 64x32 (8 waves as 2M x 4N)
  constexpr int AI = 2, BI = 2;

  __shared__ u16 As[2][128 * BK];
  __shared__ u16 Bs[2][128 * BK];

  const int tid  = threadIdx.x;
  const int lane = tid & 63;
  const int wave = tid >> 6;
  const int wm = wave >> 2;
  const int wn = wave & 3;

  const int gx = gridDim.x;
  const int nwg = gx * gridDim.y;
  const int n = blockIdx.x + gx * blockIdx.y;
  const int s_id = (n & 7) * (nwg >> 3) + (n >> 3);
  const int bx = s_id % gx;
  const int by = s_id / gx;

  const bool ist = bx >= 16;
  const int rb = ist ? bx - 16 : bx;
  const u16* Ab = (ist ? At : Ai) + (long long)rb * 128 * lda;
  const u16* Bb = (ist ? Bt : Bi) + (long long)by * 128 * ldb;
  const float* bias = ist ? bias_t : bias_i;
  const float* res  = ist ? res_t  : res_i;
  const float* gate = ist ? gate_t : gate_i;
  void* C = ist ? Ct : Ci;

  const int srow = wave * 8 + (lane >> 3);
  const int sgo  = ((lane & 7) ^ ((lane >> 3) & 7)) * 8;   // u16 units
  const u16* agp[AI]; const u16* bgp[BI];
  int alo[AI], blo[BI];
  #pragma unroll
  for (int i = 0; i < AI; ++i){
    agp[i] = Ab + (long long)(i * 64 + srow) * lda + sgo;
    alo[i] = (i * 64 + wave * 8) * BK;
  }
  #pragma unroll
  for (int i = 0; i < BI; ++i){
    bgp[i] = Bb + (long long)(i * 64 + srow) * ldb + sgo;
    blo[i] = (i * 64 + wave * 8) * BK;
  }

  const int arow0 = wm * 64;
  const int frow  = lane & 15;
  const int fx    = lane & 7;
  const int j0    = lane >> 4;

  f32x4 acc[MR][NR] = {};

  #pragma unroll
  for (int i = 0; i < AI; ++i) gld16(agp[i], &As[0][alo[i]]);
  #pragma unroll
  for (int i = 0; i < BI; ++i) gld16(bgp[i], &Bs[0][blo[i]]);
  __builtin_amdgcn_sched_barrier(0);

  const int nt = K / BK;
  for (int t = 0; t < nt; ++t){
    if (t + 1 < nt){
      int k0 = (t + 1) * BK;
      int nb = (t + 1) & 1;
      #pragma unroll
      for (int i = 0; i < AI; ++i) gld16(agp[i] + k0, &As[nb][alo[i]]);
      #pragma unroll
      for (int i = 0; i < BI; ++i) gld16(bgp[i] + k0, &Bs[nb][blo[i]]);
      __builtin_amdgcn_sched_barrier(0);
      asm volatile("s_waitcnt vmcnt(4)" ::: "memory");
    } else {
      asm volatile("s_waitcnt vmcnt(0)" ::: "memory");
    }
    __builtin_amdgcn_sched_barrier(0);
    __builtin_amdgcn_s_barrier();
    __builtin_amdgcn_sched_barrier(0);

    const u16* as = As[t & 1];
    const u16* bs = Bs[t & 1];
    #pragma unroll
    for (int s = 0; s < 2; ++s){
      const int oct = (s * 4 + j0) ^ fx;
      bf16x8 bfr[NR];
      #pragma unroll
      for (int nn = 0; nn < NR; ++nn)
        bfr[nn] = *(const bf16x8*)&bs[(wn * 32 + nn * 16 + frow) * BK + oct * 8];
      __builtin_amdgcn_s_setprio(1);
      #pragma unroll
      for (int m = 0; m < MR; ++m){
        bf16x8 af = *(const bf16x8*)&as[(arow0 + m * 16 + frow) * BK + oct * 8];
        #pragma unroll
        for (int nn = 0; nn < NR; ++nn)
          acc[m][nn] = __builtin_amdgcn_mfma_f32_16x16x32_bf16(af, bfr[nn], acc[m][nn], 0, 0, 0);
      }
      __builtin_amdgcn_s_setprio(0);
    }
    __builtin_amdgcn_sched_barrier(0);
    __builtin_amdgcn_s_barrier();
    __builtin_amdgcn_sched_barrier(0);
  }

  const int lr = (lane >> 4) * 4;
  const int lc = lane & 15;
  const long long rowb = (long long)rb * 128 + arow0;
  const long long colb = (long long)by * 128 + wn * 32;
  #pragma unroll
  for (int mi = 0; mi < MR; ++mi){
    #pragma unroll
    for (int ni = 0; ni < NR; ++ni){
      long long col = colb + ni * 16 + lc;
      float bv = bias ? bias[col] : 0.0f;
      #pragma unroll
      for (int j = 0; j < 4; ++j){
        long long row = rowb + mi * 16 + lr + j;
        float v = acc[mi][ni][j] + bv;
        long long ci = row * (long long)ldc + col;
        if constexpr (MODE == 0) ((float*)C)[ci] = v;
        else if constexpr (MODE == 1) ((u16*)C)[ci] = f2bf(v);
        else if constexpr (MODE == 2) ((float*)C)[ci] = res[ci] + gate[col] * v;
        else {
          float z2 = 1.5957691216057308f * (v + 0.044715f * v * v * v);
          ((u16*)C)[ci] = f2bf(v / (1.0f + __expf(-z2)));
        }
      }
    }
  }
}

extern "C" void kernel_launch(void* const* d_in, const int* in_sizes, int n_in,
                              void* d_out, int out_size, void* d_ws, size_t ws_size,
                              hipStream_t stream)
{
  const float* img        = (const float*)d_in[0];
  const float* txt        = (const float*)d_in[1];
  const float* vec        = (const float*)d_in[2];
  const float* img_mod_w  = (const float*)d_in[3];
  const float* img_mod_b  = (const float*)d_in[4];
  const float* txt_mod_w  = (const float*)d_in[5];
  const float* txt_mod_b  = (const float*)d_in[6];
  const float* img_qkv_w  = (const float*)d_in[7];
  const float* img_qkv_b  = (const float*)d_in[8];
  const float* img_q_s    = (const float*)d_in[9];
  const float* img_k_s    = (const float*)d_in[10];
  const float* txt_qkv_w  = (const float*)d_in[11];
  const float* txt_qkv_b  = (const float*)d_in[12];
  const float* txt_q_s    = (const float*)d_in[13];
  const float* txt_k_s    = (const float*)d_in[14];
  const float* img_proj_w = (const float*)d_in[15];
  const float* img_proj_b = (const float*)d_in[16];
  const float* txt_proj_w = (const float*)d_in[17];
  const float* txt_proj_b = (const float*)d_in[18];
  const float* img_mlp_w1 = (const float*)d_in[19];
  const float* img_mlp_b1 = (const float*)d_in[20];
  const float* img_mlp_w2 = (const float*)d_in[21];
  const float* img_mlp_b2 = (const float*)d_in[22];
  const float* txt_mlp_w1 = (const float*)d_in[23];
  const float* txt_mlp_b1 = (const float*)d_in[24];
  const float* txt_mlp_w2 = (const float*)d_in[25];
  const float* txt_mlp_b2 = (const float*)d_in[26];
  const float* pe         = (const float*)d_in[27];

  char* ws = (char*)d_ws;
  size_t off = 0;
  auto alloc = [&](size_t b){ void* p = ws + off; off = (off + b + 255) & ~(size_t)255; return p; };

  u16* wq_i = (u16*)alloc(6144ll * 2048 * 2);
  u16* wq_t = (u16*)alloc(6144ll * 2048 * 2);
  u16* wp_i = (u16*)alloc(2048ll * 2048 * 2);
  u16* wp_t = (u16*)alloc(2048ll * 2048 * 2);
  u16* w1_i = (u16*)alloc(8192ll * 2048 * 2);
  u16* w1_t = (u16*)alloc(8192ll * 2048 * 2);
  u16* w2_i = (u16*)alloc(2048ll * 8192 * 2);
  u16* w2_t = (u16*)alloc(2048ll * 8192 * 2);
  float* mod_i = (float*)alloc(12288 * 4);
  float* mod_t = (float*)alloc(12288 * 4);
  u16* Qb   = (u16*)alloc(16ll * 2304 * 128 * 2);
  u16* Kb   = (u16*)alloc(16ll * 2304 * 128 * 2);
  u16* Vt   = (u16*)alloc(16ll * 2304 * 128 * 2);
  u16* attn = (u16*)alloc(2304ll * 2048 * 2);
  char* big = (char*)alloc(4ll * 2304 * 2304 * 4);   // 84.9 MB reused region

  // phase 1 views (qkv bf16)
  u16*   xin_i = (u16*)big;
  u16*   xin_t = (u16*)(big + 8388608);
  u16*   qkv_i = (u16*)(big + 9437184);
  u16*   qkv_t = (u16*)(big + 9437184 + 25165824);
  // phase 3 views
  float* y1_i  = (float*)big;
  float* y1_t  = (float*)(big + 16777216);
  u16*   ln2_i = (u16*)(big + 18874368);
  u16*   ln2_t = (u16*)(big + 27262976);
  u16*   h_i   = (u16*)(big + 28311552);
  u16*   h_t   = (u16*)(big + 61865984);

  // modulation vectors
  mod_matvec_k<<<384, 256, 0, stream>>>(vec, img_mod_w, img_mod_b, txt_mod_w, txt_mod_b, mod_i, mod_t);

  // merged weight cast + transpose to (N x K) bf16, 64x64 tiles
  {
    TcArgs a;
    const float* ins[8] = {img_qkv_w, txt_qkv_w, img_proj_w, txt_proj_w,
                           img_mlp_w1, txt_mlp_w1, img_mlp_w2, txt_mlp_w2};
    u16* outs[8] = {wq_i, wq_t, wp_i, wp_t, w1_i, w1_t, w2_i, w2_t};
    int Ks[8] = {2048, 2048, 2048, 2048, 2048, 2048, 8192, 8192};
    int Ns[8] = {6144, 6144, 2048, 2048, 8192, 8192, 2048, 2048};
    int b = 0;
    for (int i = 0; i < 8; ++i){
      a.in[i] = ins[i]; a.out[i] = outs[i]; a.K[i] = Ks[i]; a.N[i] = Ns[i];
      a.base[i] = b;
      b += (Ks[i] >> 6) * (Ns[i] >> 6);
    }
    a.base[8] = b;
    tcast64_k<<<b, 256, 0, stream>>>(a);
  }

  // LN1 + modulate (img+txt merged)
  ln_mod_k<<<2304, 256, 0, stream>>>(img, txt, mod_i, mod_i + 2048, mod_t, mod_t + 2048, xin_i, xin_t);

  // QKV GEMM (bf16 out; img+txt merged: 18x48 = 864 blocks)
  gemm8_k<1><<<dim3(18, 48), 512, 0, stream>>>(xin_i, xin_t, 2048, wq_i, wq_t, 2048,
      img_qkv_b, txt_qkv_b, nullptr, nullptr, nullptr, nullptr, qkv_i, qkv_t, 6144, 2048);

  // RMSNorm + RoPE + scatter (merged: grid 36x16)
  qkv_post_k<<<dim3(36, 16), 256, 0, stream>>>(qkv_i, qkv_t, img_q_s, img_k_s, txt_q_s, txt_k_s,
      pe, Qb, Kb, Vt);

  // fused flash attention (KV=64, 80KB LDS)
  fattn_k<<<dim3(18, 16), 512, 0, stream>>>(Qb, Kb, Vt, attn);

  // projections with residual + gate (merged: 18x16 = 288 blocks)
  gemm8_k<2><<<dim3(18, 16), 512, 0, stream>>>(attn + 256 * 2048, attn, 2048, wp_i, wp_t, 2048,
      img_proj_b, txt_proj_b, img, txt, mod_i + 4096, mod_t + 4096, y1_i, y1_t, 2048, 2048);

  // LN2 + modulate (merged)
  ln_mod_k<<<2304, 256, 0, stream>>>(y1_i, y1_t, mod_i + 6144, mod_i + 8192, mod_t + 6144, mod_t + 8192, ln2_i, ln2_t);

  // MLP1 (GELU fused; merged: 18x64 = 1152 blocks)
  gemm8_k<3><<<dim3(18, 64), 512, 0, stream>>>(ln2_i, ln2_t, 2048, w1_i, w1_t, 2048,
      img_mlp_b1, txt_mlp_b1, nullptr, nullptr, nullptr, nullptr, h_i, h_t, 8192, 2048);

  // MLP2 with residual + gate -> final outputs (merged: 18x16 = 288 blocks)
  float* out_img = (float*)d_out;
  float* out_txt = out_img + 2048ll * 2048;
  gemm8_k<2><<<dim3(18, 16), 512, 0, stream>>>(h_i, h_t, 8192, w2_i, w2_t, 8192,
      img_mlp_b2, txt_mlp_b2, y1_i, y1_t, mod_i + 10240, mod_t + 10240, out_img, out_txt, 2048, 8192);
}